// Round 9
// baseline (120.008 us; speedup 1.0000x reference)
//
#include <hip/hip_runtime.h>
#include <stdint.h>
#include <math.h>

// PhysicsForwardModel: B=2, Nz=Nx=128, Ly=Lx=512.
// out[b,t,l] = (1/3) * sum_j Cy[j,l] * sum_k cos(F[k,j]*t) * a[k] * (Cy[:,:128] x[b] Cy[:,128:256]^T)[k,j]
//              + std_b * N(0,1)  (JAX threefry key=42, partitionable counters, XLA erfinv)
// R18: stageB/noise = verified forms. stageC reshaped to kill the LDS-broadcast-pipe bound
//      (R17's 30us = ~20us of b128 broadcasts): thread owns 4 l (4 parallel Chebyshev
//      recurrences, SAME anchor exprs/values as R17) x the 4-value V-quad -> each b128 feeds
//      16 fma (was 4). 4-way j-split across thread groups (512 thr, grid 256) + fixed-order
//      js-reduce + single exact *0.0625. Numeric class same as R17 (passed at absmax 0.0039).

#define HALF_N 262144  // 512*512 per-batch elements
#define PI_F 3.14159274101257324f

// ws layout (floats): Vt [0..524288) [j][b][t]; partial [524288..525312) 256 x {s0,q0,s1,q1}

__device__ __forceinline__ uint32_t rotl32(uint32_t v, int r) {
  return (v << r) | (v >> (32 - r));
}

// XLA ErfInv32 (Giles) -- matches reference's lax.erf_inv
__device__ __forceinline__ float erfinv_xla(float x) {
  float w = -log1pf(__fmul_rn(-x, x));
  float p;
  if (w < 5.0f) {
    w = w - 2.5f;
    p = 2.81022636e-08f;
    p = fmaf(p, w, 3.43273939e-07f);
    p = fmaf(p, w, -3.5233877e-06f);
    p = fmaf(p, w, -4.39150654e-06f);
    p = fmaf(p, w, 0.00021858087f);
    p = fmaf(p, w, -0.00125372503f);
    p = fmaf(p, w, -0.00417768164f);
    p = fmaf(p, w, 0.246640727f);
    p = fmaf(p, w, 1.50140941f);
  } else {
    w = __fsqrt_rn(w) - 3.0f;
    p = -0.000200214257f;
    p = fmaf(p, w, 0.000100950558f);
    p = fmaf(p, w, 0.00134934322f);
    p = fmaf(p, w, -0.00367342844f);
    p = fmaf(p, w, 0.00573950773f);
    p = fmaf(p, w, -0.0076224613f);
    p = fmaf(p, w, 0.00943887047f);
    p = fmaf(p, w, 1.00167406f);
    p = fmaf(p, w, 2.83297682f);
  }
  return p * x;
}

// Cy[k,n] = sc(k) * 2 * cos(pi*(2n+1)*k/1024), with n2p1 = (float)(2n+1) exact
__device__ __forceinline__ float cy_elem(float n2p1, float kf, float sc) {
  float t1 = __fmul_rn(PI_F, n2p1);
  float arg = __fmul_rn(t1, kf) * (1.0f / 1024.0f);
  return __fmul_rn(sc, __fmul_rn(2.0f, __cosf(arg)));
}

// fusedB, block = j (grid 512, 512 threads):  [R1-verified, byte-identical]
__global__ __launch_bounds__(512, 4) void stageB_kernel(const float* __restrict__ x,
                                                        float* __restrict__ Vt) {
  __shared__ float cyl[128];
  __shared__ float us[256];
  __shared__ float fs[512];
  __shared__ float msf[1024];
  int j = blockIdx.x;
  int tid = threadIdx.x;
  float jf = (float)j;
  if (tid < 128) {
    float scj = (j == 0) ? (1.0f / __fsqrt_rn(2048.0f)) : 0.03125f;
    cyl[tid] = cy_elem((float)(2 * (128 + tid) + 1), jf, scj);
  }
  __syncthreads();
  if (tid < 256) {
    int b = tid >> 7, i = tid & 127;
    const float* xr = x + (b * 128 + i) * 128;
    float accA = 0.0f, accB = 0.0f;
    for (int jj = 0; jj < 128; jj += 8) {
      float4 xa = *(const float4*)&xr[jj];
      float4 xb = *(const float4*)&xr[jj + 4];
      float4 ca = *(const float4*)&cyl[jj];
      float4 cb = *(const float4*)&cyl[jj + 4];
      accA = fmaf(xa.x, ca.x, accA); accB = fmaf(xa.y, ca.y, accB);
      accA = fmaf(xa.z, ca.z, accA); accB = fmaf(xa.w, ca.w, accB);
      accA = fmaf(xb.x, cb.x, accA); accB = fmaf(xb.y, cb.y, accB);
      accA = fmaf(xb.z, cb.z, accA); accB = fmaf(xb.w, cb.w, accB);
    }
    us[tid] = accA + accB;
  }
  __syncthreads();
  {
    float kf = (float)tid;
    float sc = (tid == 0) ? (1.0f / __fsqrt_rn(2048.0f)) : 0.03125f;
    float a = cy_elem(1.0f, kf, sc);  // i=0: a[k] = Cy[k,0]
    float acc0 = __fmul_rn(a, us[0]);
    float acc1 = __fmul_rn(a, us[128]);
    // i = 1..3 singles, then aligned batches of 4
    float accA0 = 0.f, accA1 = 0.f;
    {
      float c1 = cy_elem(3.0f, kf, sc);
      float c2 = cy_elem(5.0f, kf, sc);
      float c3 = cy_elem(7.0f, kf, sc);
      acc0 = fmaf(c1, us[1], acc0);   acc1 = fmaf(c1, us[129], acc1);
      accA0 = fmaf(c2, us[2], accA0); accA1 = fmaf(c2, us[130], accA1);
      acc0 = fmaf(c3, us[3], acc0);   acc1 = fmaf(c3, us[131], acc1);
    }
    for (int i = 4; i < 128; i += 4) {
      float b0 = (float)(2 * i + 1);
      float c0 = cy_elem(b0, kf, sc);
      float c1 = cy_elem(__fadd_rn(b0, 2.0f), kf, sc);
      float c2 = cy_elem(__fadd_rn(b0, 4.0f), kf, sc);
      float c3 = cy_elem(__fadd_rn(b0, 6.0f), kf, sc);
      float4 u0 = *(const float4*)&us[i];
      float4 u1 = *(const float4*)&us[128 + i];
      acc0 = fmaf(c0, u0.x, acc0);   acc1 = fmaf(c0, u1.x, acc1);
      accA0 = fmaf(c1, u0.y, accA0); accA1 = fmaf(c1, u1.y, accA1);
      acc0 = fmaf(c2, u0.z, acc0);   acc1 = fmaf(c2, u1.z, acc1);
      accA0 = fmaf(c3, u0.w, accA0); accA1 = fmaf(c3, u1.w, accA1);
    }
    acc0 += accA0;
    acc1 += accA1;
    const float w0 = PI_F / 512.0f;  // exact pow2 scale of pi_f
    float ky = __fmul_rn(kf, w0);
    float kx = __fmul_rn(jf, w0);
    fs[tid] = __fsqrt_rn(__fadd_rn(__fmul_rn(ky, ky), __fmul_rn(kx, kx)));
    msf[2 * tid] = __fmul_rn(a, acc0);
    msf[2 * tid + 1] = __fmul_rn(a, acc1);
  }
  __syncthreads();
  float tf = (float)tid;
  float acc0 = 0.f, acc1 = 0.f, acc2 = 0.f, acc3 = 0.f;
  for (int k0 = 0; k0 < 512; k0 += 8) {
    float4 f0 = *(const float4*)&fs[k0];
    float4 f1 = *(const float4*)&fs[k0 + 4];
    float4 m0 = *(const float4*)&msf[2 * k0];
    float4 m1 = *(const float4*)&msf[2 * k0 + 4];
    float4 m2 = *(const float4*)&msf[2 * k0 + 8];
    float4 m3 = *(const float4*)&msf[2 * k0 + 12];
    float ph0 = __cosf(__fmul_rn(f0.x, tf));  // arg bit-matches ref's f32 F*t
    float ph1 = __cosf(__fmul_rn(f0.y, tf));
    float ph2 = __cosf(__fmul_rn(f0.z, tf));
    float ph3 = __cosf(__fmul_rn(f0.w, tf));
    float ph4 = __cosf(__fmul_rn(f1.x, tf));
    float ph5 = __cosf(__fmul_rn(f1.y, tf));
    float ph6 = __cosf(__fmul_rn(f1.z, tf));
    float ph7 = __cosf(__fmul_rn(f1.w, tf));
    acc0 = fmaf(ph0, m0.x, acc0); acc1 = fmaf(ph0, m0.y, acc1);
    acc2 = fmaf(ph1, m0.z, acc2); acc3 = fmaf(ph1, m0.w, acc3);
    acc0 = fmaf(ph2, m1.x, acc0); acc1 = fmaf(ph2, m1.y, acc1);
    acc2 = fmaf(ph3, m1.z, acc2); acc3 = fmaf(ph3, m1.w, acc3);
    acc0 = fmaf(ph4, m2.x, acc0); acc1 = fmaf(ph4, m2.y, acc1);
    acc2 = fmaf(ph5, m2.z, acc2); acc3 = fmaf(ph5, m2.w, acc3);
    acc0 = fmaf(ph6, m3.x, acc0); acc1 = fmaf(ph6, m3.y, acc1);
    acc2 = fmaf(ph7, m3.z, acc2); acc3 = fmaf(ph7, m3.w, acc3);
  }
  Vt[(j << 10) + tid] = acc0 + acc2;
  Vt[(j << 10) + 512 + tid] = acc1 + acc3;
}

// stageC v3: block = t-pair (grid 256, 512 threads).
//   Thread (lq = tid&127, js = tid>>7): 4 l's (l = 4lq+li) x j-quarter [128js, 128js+128).
//   Per j: 1 broadcast b128 (V quad) + 4 recurrence fma + 16 acc fma.
//   Anchors every 16 j with R17's exact arg expressions -> identical coefficient values.
//   js-partials reduced in fixed order, single exact *0.0625, then /3.
__global__ __launch_bounds__(512, 2) void stageC_kernel(const float* __restrict__ Vt,
                                                        float* __restrict__ out,
                                                        float* __restrict__ partial) {
  __shared__ float vq[2048];           // [j][4] = {b0t0, b1t0, b0t1, b1t1}
  __shared__ float red[4][128][16];    // [js][lq][li*4+s]  (32 KB)
  __shared__ float redw[8][4];
  int t0 = blockIdx.x << 1;
  int tid = threadIdx.x;
  {
    const float* base = Vt + (tid << 10);
    vq[(tid << 2) + 0] = base[t0];
    vq[(tid << 2) + 1] = base[512 + t0];
    vq[(tid << 2) + 2] = base[t0 + 1];
    vq[(tid << 2) + 3] = base[512 + t0 + 1];
  }
  __syncthreads();
  int lq = tid & 127;
  int js = tid >> 7;
  int jbeg = js << 7;
  float t1v[4], k2[4], c_m1[4], c_m2[4];
  float acc[4][4];
#pragma unroll
  for (int li = 0; li < 4; ++li) {
    t1v[li] = __fmul_rn(PI_F, (float)(2 * (4 * lq + li) + 1));
    float cth = __cosf(__fmul_rn(t1v[li], 1.0f) * (1.0f / 1024.0f));
    k2[li] = cth + cth;  // exact *2; cth recoverable as k2*0.5 exactly
#pragma unroll
    for (int s = 0; s < 4; ++s) acc[li][s] = 0.0f;
  }
  for (int blk = 0; blk < 8; ++blk) {
    int j0 = jbeg + (blk << 4);
    if (j0 == 0) {  // wave-uniform (js uniform per wave)
      // j=0: coefficient cy0, pre-scaled by exact 16 (undone by final *0.0625)
      float cy0 = __fmul_rn(1.0f / __fsqrt_rn(2048.0f), 2.0f);
      float c16 = __fmul_rn(cy0, 16.0f);
      float4 v0 = *(const float4*)&vq[0];
#pragma unroll
      for (int li = 0; li < 4; ++li) {
        acc[li][0] = fmaf(c16, v0.x, acc[li][0]);
        acc[li][1] = fmaf(c16, v0.y, acc[li][1]);
        acc[li][2] = fmaf(c16, v0.z, acc[li][2]);
        acc[li][3] = fmaf(c16, v0.w, acc[li][3]);
      }
      // j=1 anchor (== cth), j=2 anchor, recur 3..15
      float4 v1 = *(const float4*)&vq[4];
#pragma unroll
      for (int li = 0; li < 4; ++li) {
        float cth = __fmul_rn(k2[li], 0.5f);
        acc[li][0] = fmaf(cth, v1.x, acc[li][0]);
        acc[li][1] = fmaf(cth, v1.y, acc[li][1]);
        acc[li][2] = fmaf(cth, v1.z, acc[li][2]);
        acc[li][3] = fmaf(cth, v1.w, acc[li][3]);
        c_m2[li] = cth;
      }
      float4 v2 = *(const float4*)&vq[8];
#pragma unroll
      for (int li = 0; li < 4; ++li) {
        float c2v = __cosf(__fmul_rn(t1v[li], 2.0f) * (1.0f / 1024.0f));
        acc[li][0] = fmaf(c2v, v2.x, acc[li][0]);
        acc[li][1] = fmaf(c2v, v2.y, acc[li][1]);
        acc[li][2] = fmaf(c2v, v2.z, acc[li][2]);
        acc[li][3] = fmaf(c2v, v2.w, acc[li][3]);
        c_m1[li] = c2v;
      }
#pragma unroll
      for (int n = 3; n < 16; ++n) {
        float4 v = *(const float4*)&vq[n << 2];
#pragma unroll
        for (int li = 0; li < 4; ++li) {
          float cn = fmaf(k2[li], c_m1[li], -c_m2[li]);
          acc[li][0] = fmaf(cn, v.x, acc[li][0]);
          acc[li][1] = fmaf(cn, v.y, acc[li][1]);
          acc[li][2] = fmaf(cn, v.z, acc[li][2]);
          acc[li][3] = fmaf(cn, v.w, acc[li][3]);
          c_m2[li] = c_m1[li]; c_m1[li] = cn;
        }
      }
    } else {
      float jb = (float)j0;
      float4 va = *(const float4*)&vq[j0 << 2];
#pragma unroll
      for (int li = 0; li < 4; ++li) {
        float ca = __cosf(__fmul_rn(t1v[li], jb) * (1.0f / 1024.0f));
        acc[li][0] = fmaf(ca, va.x, acc[li][0]);
        acc[li][1] = fmaf(ca, va.y, acc[li][1]);
        acc[li][2] = fmaf(ca, va.z, acc[li][2]);
        acc[li][3] = fmaf(ca, va.w, acc[li][3]);
        c_m2[li] = ca;
      }
      float4 vb = *(const float4*)&vq[(j0 + 1) << 2];
#pragma unroll
      for (int li = 0; li < 4; ++li) {
        float cb = __cosf(__fmul_rn(t1v[li], __fadd_rn(jb, 1.0f)) * (1.0f / 1024.0f));
        acc[li][0] = fmaf(cb, vb.x, acc[li][0]);
        acc[li][1] = fmaf(cb, vb.y, acc[li][1]);
        acc[li][2] = fmaf(cb, vb.z, acc[li][2]);
        acc[li][3] = fmaf(cb, vb.w, acc[li][3]);
        c_m1[li] = cb;
      }
#pragma unroll
      for (int n = 2; n < 16; ++n) {
        float4 v = *(const float4*)&vq[(j0 + n) << 2];
#pragma unroll
        for (int li = 0; li < 4; ++li) {
          float cn = fmaf(k2[li], c_m1[li], -c_m2[li]);
          acc[li][0] = fmaf(cn, v.x, acc[li][0]);
          acc[li][1] = fmaf(cn, v.y, acc[li][1]);
          acc[li][2] = fmaf(cn, v.z, acc[li][2]);
          acc[li][3] = fmaf(cn, v.w, acc[li][3]);
          c_m2[li] = c_m1[li]; c_m1[li] = cn;
        }
      }
    }
  }
  // stash js-partials
#pragma unroll
  for (int li = 0; li < 4; ++li) {
#pragma unroll
    for (int s = 0; s < 4; ++s) red[js][lq][li * 4 + s] = acc[li][s];
  }
  __syncthreads();
  // remap: thread (lq2 = tid>>2, q = tid&3) -> one (b,t) row of 4 consecutive l
  int lq2 = tid >> 2, q = tid & 3;  // q = (dt<<1)|b slot
  float o0, o1, o2, o3;
  {
    float s0 = red[0][lq2][0 * 4 + q], s1 = red[1][lq2][0 * 4 + q];
    float s2 = red[2][lq2][0 * 4 + q], s3 = red[3][lq2][0 * 4 + q];
    o0 = ((s0 + s1) + s2) + s3;
  }
  {
    float s0 = red[0][lq2][1 * 4 + q], s1 = red[1][lq2][1 * 4 + q];
    float s2 = red[2][lq2][1 * 4 + q], s3 = red[3][lq2][1 * 4 + q];
    o1 = ((s0 + s1) + s2) + s3;
  }
  {
    float s0 = red[0][lq2][2 * 4 + q], s1 = red[1][lq2][2 * 4 + q];
    float s2 = red[2][lq2][2 * 4 + q], s3 = red[3][lq2][2 * 4 + q];
    o2 = ((s0 + s1) + s2) + s3;
  }
  {
    float s0 = red[0][lq2][3 * 4 + q], s1 = red[1][lq2][3 * 4 + q];
    float s2 = red[2][lq2][3 * 4 + q], s3 = red[3][lq2][3 * 4 + q];
    o3 = ((s0 + s1) + s2) + s3;
  }
  o0 = __fmul_rn(o0, 0.0625f) / 3.0f;
  o1 = __fmul_rn(o1, 0.0625f) / 3.0f;
  o2 = __fmul_rn(o2, 0.0625f) / 3.0f;
  o3 = __fmul_rn(o3, 0.0625f) / 3.0f;
  int dt = q >> 1, b = q & 1;
  *(float4*)&out[b * HALF_N + ((t0 + dt) << 9) + (lq2 << 2)] = make_float4(o0, o1, o2, o3);
  // stats: thread's 4 outputs belong to one batch b
  float ssum = (o0 + o1) + (o2 + o3);
  float qsum = fmaf(o0, o0, o1 * o1) + fmaf(o2, o2, o3 * o3);
  float s0 = (b == 0) ? ssum : 0.0f, s1 = (b == 1) ? ssum : 0.0f;
  float q0 = (b == 0) ? qsum : 0.0f, q1 = (b == 1) ? qsum : 0.0f;
  for (int off = 32; off > 0; off >>= 1) {
    s0 += __shfl_down(s0, off);
    q0 += __shfl_down(q0, off);
    s1 += __shfl_down(s1, off);
    q1 += __shfl_down(q1, off);
  }
  int wave = tid >> 6;
  if ((tid & 63) == 0) {
    redw[wave][0] = s0; redw[wave][1] = q0; redw[wave][2] = s1; redw[wave][3] = q1;
  }
  __syncthreads();
  if (tid == 0) {
    float a0 = 0.f, a1 = 0.f, a2 = 0.f, a3 = 0.f;
    for (int wv = 0; wv < 8; ++wv) {
      a0 += redw[wv][0]; a1 += redw[wv][1]; a2 += redw[wv][2]; a3 += redw[wv][3];
    }
    partial[blockIdx.x * 4 + 0] = a0;
    partial[blockIdx.x * 4 + 1] = a1;
    partial[blockIdx.x * 4 + 2] = a2;
    partial[blockIdx.x * 4 + 3] = a3;
  }
}

// Fused stats + noise: redundant partial reduce (256 quads) -> (std0,std1), then threefry noise.
// element i -> threefry2x32(key=(0,42), ctr=(0,i)), bits = o0^o1
__global__ __launch_bounds__(256) void noise_kernel(float* __restrict__ out,
                                                    const float* __restrict__ partial) {
  int tid = threadIdx.x;
  const float4* pq = (const float4*)partial;  // 256 quads {s0,q0,s1,q1}
  float4 pa = pq[tid];
  float s0 = pa.x, q0 = pa.y, s1 = pa.z, q1 = pa.w;
  for (int off = 32; off > 0; off >>= 1) {
    s0 += __shfl_down(s0, off);
    q0 += __shfl_down(q0, off);
    s1 += __shfl_down(s1, off);
    q1 += __shfl_down(q1, off);
  }
  __shared__ float red[4][4];
  int wave = tid >> 6;
  if ((tid & 63) == 0) {
    red[wave][0] = s0; red[wave][1] = q0; red[wave][2] = s1; red[wave][3] = q1;
  }
  __syncthreads();
  float S = red[0][0] + red[1][0] + red[2][0] + red[3][0];
  float Q = red[0][1] + red[1][1] + red[2][1] + red[3][1];
  float S2 = red[0][2] + red[1][2] + red[2][2] + red[3][2];
  float Q2 = red[0][3] + red[1][3] + red[2][3] + red[3][3];
  const float invN = 1.0f / 262144.0f;
  float m0 = S * invN, m1 = S2 * invN;
  float std0 = __fsqrt_rn(fmaxf(Q * invN - m0 * m0, 0.0f));
  float std1 = __fsqrt_rn(fmaxf(Q2 * invN - m1 * m1, 0.0f));

  int i = blockIdx.x * 256 + tid;  // < 524288
  uint32_t x0 = 0u;
  uint32_t x1 = (uint32_t)i;
  const uint32_t k0 = 0u, k1 = 42u;
  const uint32_t k2 = k0 ^ k1 ^ 0x1BD11BDAu;
  x0 += k0; x1 += k1;
#define QR(r) x0 += x1; x1 = rotl32(x1, r); x1 ^= x0;
  QR(13) QR(15) QR(26) QR(6)
  x0 += k1; x1 += k2 + 1u;
  QR(17) QR(29) QR(16) QR(24)
  x0 += k2; x1 += k0 + 2u;
  QR(13) QR(15) QR(26) QR(6)
  x0 += k0; x1 += k1 + 3u;
  QR(17) QR(29) QR(16) QR(24)
  x0 += k1; x1 += k2 + 4u;
  QR(13) QR(15) QR(26) QR(6)
  x0 += k2; x1 += k0 + 5u;
#undef QR
  uint32_t bits = x0 ^ x1;
  const float lo = __uint_as_float(0xBF7FFFFFu);  // nextafter(-1,0)
  float f = __uint_as_float((bits >> 9) | 0x3F800000u) - 1.0f;
  float u = fmaxf(lo, __fadd_rn(__fmul_rn(f, 2.0f), lo));
  const float sqrt2 = 1.41421356237309515f;
  out[i] += (i < HALF_N ? std0 : std1) * (sqrt2 * erfinv_xla(u));
}

extern "C" void kernel_launch(void* const* d_in, const int* in_sizes, int n_in,
                              void* d_out, int out_size, void* d_ws, size_t ws_size,
                              hipStream_t stream) {
  const float* x = (const float*)d_in[0];
  float* ws = (float*)d_ws;
  float* Vt      = ws;
  float* partial = ws + 524288;
  float* out = (float*)d_out;

  stageB_kernel<<<512, 512, 0, stream>>>(x, Vt);
  stageC_kernel<<<256, 512, 0, stream>>>(Vt, out, partial);
  noise_kernel<<<2048, 256, 0, stream>>>(out, partial);
}

// Round 10
// 110.933 us; speedup vs baseline: 1.0818x; 1.0818x over previous
//
#include <hip/hip_runtime.h>
#include <stdint.h>
#include <math.h>

// PhysicsForwardModel: B=2, Nz=Nx=128, Ly=Lx=512.
// out[b,t,l] = (1/3) * sum_j Cy[j,l] * sum_k cos(F[k,j]*t) * a[k] * (Cy[:,:128] x[b] Cy[:,128:256]^T)[k,j]
//              + std_b * N(0,1)  (JAX threefry key=42, partitionable counters, XLA erfinv)
// R19: stageC/noise = R17's verified kernels byte-for-byte (R18's stageC reshape was neutral;
//      reverted). ONE change: stageB phase C now uses the R17-validated Chebyshev trick along
//      t: thread owns a STRIDED t-octet {tg+64n} and a 64-k chunk; per k, anchors
//      cos(F·tg), cos(F·(tg+64)) (ref-exact args) + step 2cos(64F), recur 6 -> 50M cos
//      (was 134M). Strided octet makes red[kg][t] reduction conflict-free. k-sum regrouped
//      (8 chunks, ascending) -- ulp-class vs the verified 1e-5 coefficient deltas.
//      Phases A/A2/B byte-identical math (packed to an LDS float4 quad).

#define HALF_N 262144  // 512*512 per-batch elements
#define PI_F 3.14159274101257324f

// ws layout (floats): Vt [0..524288) [j][b][t]; partial [524288..526336) 512 x {s0,q0,s1,q1}

__device__ __forceinline__ uint32_t rotl32(uint32_t v, int r) {
  return (v << r) | (v >> (32 - r));
}

// XLA ErfInv32 (Giles) -- matches reference's lax.erf_inv
__device__ __forceinline__ float erfinv_xla(float x) {
  float w = -log1pf(__fmul_rn(-x, x));
  float p;
  if (w < 5.0f) {
    w = w - 2.5f;
    p = 2.81022636e-08f;
    p = fmaf(p, w, 3.43273939e-07f);
    p = fmaf(p, w, -3.5233877e-06f);
    p = fmaf(p, w, -4.39150654e-06f);
    p = fmaf(p, w, 0.00021858087f);
    p = fmaf(p, w, -0.00125372503f);
    p = fmaf(p, w, -0.00417768164f);
    p = fmaf(p, w, 0.246640727f);
    p = fmaf(p, w, 1.50140941f);
  } else {
    w = __fsqrt_rn(w) - 3.0f;
    p = -0.000200214257f;
    p = fmaf(p, w, 0.000100950558f);
    p = fmaf(p, w, 0.00134934322f);
    p = fmaf(p, w, -0.00367342844f);
    p = fmaf(p, w, 0.00573950773f);
    p = fmaf(p, w, -0.0076224613f);
    p = fmaf(p, w, 0.00943887047f);
    p = fmaf(p, w, 1.00167406f);
    p = fmaf(p, w, 2.83297682f);
  }
  return p * x;
}

// Cy[k,n] = sc(k) * 2 * cos(pi*(2n+1)*k/1024), with n2p1 = (float)(2n+1) exact
__device__ __forceinline__ float cy_elem(float n2p1, float kf, float sc) {
  float t1 = __fmul_rn(PI_F, n2p1);
  float arg = __fmul_rn(t1, kf) * (1.0f / 1024.0f);
  return __fmul_rn(sc, __fmul_rn(2.0f, __cosf(arg)));
}

// fusedB, block = j (grid 512, 512 threads):
//   A  (tid<128): cyl[jj] = Cy[j,128+jj]                       [byte-identical math]
//   A2 (tid<256): us[b*128+i] = sum_jj x[b,i,jj]*cyl[jj]       [byte-identical math]
//   B  (lane=k):  kq[k] = {F[k,j], a*acc0, a*acc1, 0}          [byte-identical math]
//   C  (kg=tid>>6, tg=tid&63): t-octet {tg+64n}, k in [64kg,64kg+64):
//        anchors cos(F*tg), cos(F*(tg+64)) [ref-exact args], step 2*cos(F*64), recur 6.
//        red[kg][t] partials reduced ascending-kg in two passes (b0, b1).
__global__ __launch_bounds__(512, 4) void stageB_kernel(const float* __restrict__ x,
                                                        float* __restrict__ Vt) {
  __shared__ float cyl[128];
  __shared__ float us[256];
  __shared__ float4 kq[512];
  __shared__ float red[8][512];
  int j = blockIdx.x;
  int tid = threadIdx.x;
  float jf = (float)j;
  if (tid < 128) {
    float scj = (j == 0) ? (1.0f / __fsqrt_rn(2048.0f)) : 0.03125f;
    cyl[tid] = cy_elem((float)(2 * (128 + tid) + 1), jf, scj);
  }
  __syncthreads();
  if (tid < 256) {
    int b = tid >> 7, i = tid & 127;
    const float* xr = x + (b * 128 + i) * 128;
    float accA = 0.0f, accB = 0.0f;
    for (int jj = 0; jj < 128; jj += 8) {
      float4 xa = *(const float4*)&xr[jj];
      float4 xb = *(const float4*)&xr[jj + 4];
      float4 ca = *(const float4*)&cyl[jj];
      float4 cb = *(const float4*)&cyl[jj + 4];
      accA = fmaf(xa.x, ca.x, accA); accB = fmaf(xa.y, ca.y, accB);
      accA = fmaf(xa.z, ca.z, accA); accB = fmaf(xa.w, ca.w, accB);
      accA = fmaf(xb.x, cb.x, accA); accB = fmaf(xb.y, cb.y, accB);
      accA = fmaf(xb.z, cb.z, accA); accB = fmaf(xb.w, cb.w, accB);
    }
    us[tid] = accA + accB;
  }
  __syncthreads();
  {
    float kf = (float)tid;
    float sc = (tid == 0) ? (1.0f / __fsqrt_rn(2048.0f)) : 0.03125f;
    float a = cy_elem(1.0f, kf, sc);  // i=0: a[k] = Cy[k,0]
    float acc0 = __fmul_rn(a, us[0]);
    float acc1 = __fmul_rn(a, us[128]);
    float accA0 = 0.f, accA1 = 0.f;
    {
      float c1 = cy_elem(3.0f, kf, sc);
      float c2 = cy_elem(5.0f, kf, sc);
      float c3 = cy_elem(7.0f, kf, sc);
      acc0 = fmaf(c1, us[1], acc0);   acc1 = fmaf(c1, us[129], acc1);
      accA0 = fmaf(c2, us[2], accA0); accA1 = fmaf(c2, us[130], accA1);
      acc0 = fmaf(c3, us[3], acc0);   acc1 = fmaf(c3, us[131], acc1);
    }
    for (int i = 4; i < 128; i += 4) {
      float b0 = (float)(2 * i + 1);
      float c0 = cy_elem(b0, kf, sc);
      float c1 = cy_elem(__fadd_rn(b0, 2.0f), kf, sc);
      float c2 = cy_elem(__fadd_rn(b0, 4.0f), kf, sc);
      float c3 = cy_elem(__fadd_rn(b0, 6.0f), kf, sc);
      float4 u0 = *(const float4*)&us[i];
      float4 u1 = *(const float4*)&us[128 + i];
      acc0 = fmaf(c0, u0.x, acc0);   acc1 = fmaf(c0, u1.x, acc1);
      accA0 = fmaf(c1, u0.y, accA0); accA1 = fmaf(c1, u1.y, accA1);
      acc0 = fmaf(c2, u0.z, acc0);   acc1 = fmaf(c2, u1.z, acc1);
      accA0 = fmaf(c3, u0.w, accA0); accA1 = fmaf(c3, u1.w, accA1);
    }
    acc0 += accA0;
    acc1 += accA1;
    const float w0 = PI_F / 512.0f;  // exact pow2 scale of pi_f
    float ky = __fmul_rn(kf, w0);
    float kx = __fmul_rn(jf, w0);
    float fsv = __fsqrt_rn(__fadd_rn(__fmul_rn(ky, ky), __fmul_rn(kx, kx)));
    kq[tid] = make_float4(fsv, __fmul_rn(a, acc0), __fmul_rn(a, acc1), 0.0f);
  }
  __syncthreads();
  // Phase C: thread (kg, tg); t = tg + 64n (n=0..7); k in [64kg, 64kg+64)
  int kg = tid >> 6, tg = tid & 63;
  int kbeg = kg << 6;
  float tfa = (float)tg;         // anchor t
  float tfb = (float)(tg + 64);  // anchor t + 64
  float a0[8], a1[8];
#pragma unroll
  for (int n = 0; n < 8; ++n) { a0[n] = 0.0f; a1[n] = 0.0f; }
  for (int kk = 0; kk < 64; ++kk) {
    float4 q = kq[kbeg + kk];
    float F = q.x, m0 = q.y, m1 = q.z;
    float cs = __cosf(__fmul_rn(F, 64.0f));
    float k2 = cs + cs;  // exact *2
    float ca = __cosf(__fmul_rn(F, tfa));  // bit-matches ref at t = tg
    float cb = __cosf(__fmul_rn(F, tfb));  // bit-matches ref at t = tg+64
    a0[0] = fmaf(ca, m0, a0[0]); a1[0] = fmaf(ca, m1, a1[0]);
    a0[1] = fmaf(cb, m0, a0[1]); a1[1] = fmaf(cb, m1, a1[1]);
#pragma unroll
    for (int n = 2; n < 8; ++n) {
      float cn = fmaf(k2, cb, -ca);
      a0[n] = fmaf(cn, m0, a0[n]); a1[n] = fmaf(cn, m1, a1[n]);
      ca = cb; cb = cn;
    }
  }
  // reduce b0 then b1 across kg (ascending, fixed order); red[kg][t] conflict-free
#pragma unroll
  for (int n = 0; n < 8; ++n) red[kg][(n << 6) + tg] = a0[n];
  __syncthreads();
  float s0 = red[0][tid];
#pragma unroll
  for (int g = 1; g < 8; ++g) s0 += red[g][tid];
  __syncthreads();
#pragma unroll
  for (int n = 0; n < 8; ++n) red[kg][(n << 6) + tg] = a1[n];
  __syncthreads();
  float s1 = red[0][tid];
#pragma unroll
  for (int g = 1; g < 8; ++g) s1 += red[g][tid];
  Vt[(j << 10) + tid] = s0;
  Vt[(j << 10) + 512 + tid] = s1;
}

// stageC: R17-verified byte-for-byte. block = (t-pair, l-half) (grid 512, 256 threads).
// Chebyshev coefficient recurrence with __cosf anchors every 16 j (ref-exact anchor args);
// raw-cos accumulation, single exact *0.0625, then /3.
__global__ __launch_bounds__(256, 4) void stageC_kernel(const float* __restrict__ Vt,
                                                        float* __restrict__ out,
                                                        float* __restrict__ partial) {
  __shared__ float vq[2048];  // [j][4] = {b0t0, b1t0, b0t1, b1t1}
  int tpair = blockIdx.x >> 1;
  int lhalf = blockIdx.x & 1;
  int t0 = tpair << 1;
  int tid = threadIdx.x;
#pragma unroll
  for (int r = 0; r < 2; ++r) {
    int j = tid + (r << 8);
    const float* base = Vt + (j << 10);
    vq[(j << 2) + 0] = base[t0];
    vq[(j << 2) + 1] = base[512 + t0];
    vq[(j << 2) + 2] = base[t0 + 1];
    vq[(j << 2) + 3] = base[512 + t0 + 1];
  }
  __syncthreads();
  int l = (lhalf << 8) + tid;
  float t1 = __fmul_rn(PI_F, (float)(2 * l + 1));
  float cth = __cosf(__fmul_rn(t1, 1.0f) * (1.0f / 1024.0f));
  float k2 = cth + cth;  // exact *2
  float cy0 = __fmul_rn(1.0f / __fsqrt_rn(2048.0f), 2.0f);
  float c16 = __fmul_rn(cy0, 16.0f);
  float4 v0 = *(const float4*)&vq[0];
  float a00 = __fmul_rn(c16, v0.x);
  float a01 = __fmul_rn(c16, v0.y);
  float a10 = __fmul_rn(c16, v0.z);
  float a11 = __fmul_rn(c16, v0.w);
  float c_m1, c_m2;
  {
    float4 v1 = *(const float4*)&vq[1 << 2];
    a00 = fmaf(cth, v1.x, a00); a01 = fmaf(cth, v1.y, a01);
    a10 = fmaf(cth, v1.z, a10); a11 = fmaf(cth, v1.w, a11);
    float c2v = __cosf(__fmul_rn(t1, 2.0f) * (1.0f / 1024.0f));
    float4 v2 = *(const float4*)&vq[2 << 2];
    a00 = fmaf(c2v, v2.x, a00); a01 = fmaf(c2v, v2.y, a01);
    a10 = fmaf(c2v, v2.z, a10); a11 = fmaf(c2v, v2.w, a11);
    c_m2 = cth; c_m1 = c2v;
#pragma unroll
    for (int j = 3; j < 16; ++j) {
      float cn = fmaf(k2, c_m1, -c_m2);
      float4 v = *(const float4*)&vq[j << 2];
      a00 = fmaf(cn, v.x, a00); a01 = fmaf(cn, v.y, a01);
      a10 = fmaf(cn, v.z, a10); a11 = fmaf(cn, v.w, a11);
      c_m2 = c_m1; c_m1 = cn;
    }
  }
  for (int j0 = 16; j0 < 512; j0 += 16) {
    float jb = (float)j0;
    float ca = __cosf(__fmul_rn(t1, jb) * (1.0f / 1024.0f));
    float cb = __cosf(__fmul_rn(t1, __fadd_rn(jb, 1.0f)) * (1.0f / 1024.0f));
    float4 va = *(const float4*)&vq[j0 << 2];
    a00 = fmaf(ca, va.x, a00); a01 = fmaf(ca, va.y, a01);
    a10 = fmaf(ca, va.z, a10); a11 = fmaf(ca, va.w, a11);
    float4 vb = *(const float4*)&vq[(j0 + 1) << 2];
    a00 = fmaf(cb, vb.x, a00); a01 = fmaf(cb, vb.y, a01);
    a10 = fmaf(cb, vb.z, a10); a11 = fmaf(cb, vb.w, a11);
    c_m2 = ca; c_m1 = cb;
#pragma unroll
    for (int n = 2; n < 16; ++n) {
      float cn = fmaf(k2, c_m1, -c_m2);
      float4 v = *(const float4*)&vq[(j0 + n) << 2];
      a00 = fmaf(cn, v.x, a00); a01 = fmaf(cn, v.y, a01);
      a10 = fmaf(cn, v.z, a10); a11 = fmaf(cn, v.w, a11);
      c_m2 = c_m1; c_m1 = cn;
    }
  }
  float p00 = __fmul_rn(a00, 0.0625f) / 3.0f;
  float p01 = __fmul_rn(a01, 0.0625f) / 3.0f;
  float p10 = __fmul_rn(a10, 0.0625f) / 3.0f;
  float p11 = __fmul_rn(a11, 0.0625f) / 3.0f;
  out[(t0 << 9) + l] = p00;
  out[((t0 + 1) << 9) + l] = p10;
  out[HALF_N + (t0 << 9) + l] = p01;
  out[HALF_N + ((t0 + 1) << 9) + l] = p11;
  float s0 = p00 + p10, q0 = fmaf(p00, p00, p10 * p10);
  float s1 = p01 + p11, q1 = fmaf(p01, p01, p11 * p11);
  for (int off = 32; off > 0; off >>= 1) {
    s0 += __shfl_down(s0, off);
    q0 += __shfl_down(q0, off);
    s1 += __shfl_down(s1, off);
    q1 += __shfl_down(q1, off);
  }
  __shared__ float red[4][4];
  int wave = tid >> 6;
  if ((tid & 63) == 0) {
    red[wave][0] = s0; red[wave][1] = q0; red[wave][2] = s1; red[wave][3] = q1;
  }
  __syncthreads();
  if (tid == 0) {
    float a0 = 0.f, a1 = 0.f, a2 = 0.f, a3 = 0.f;
    for (int wv = 0; wv < 4; ++wv) {
      a0 += red[wv][0]; a1 += red[wv][1]; a2 += red[wv][2]; a3 += red[wv][3];
    }
    partial[blockIdx.x * 4 + 0] = a0;
    partial[blockIdx.x * 4 + 1] = a1;
    partial[blockIdx.x * 4 + 2] = a2;
    partial[blockIdx.x * 4 + 3] = a3;
  }
}

// Fused stats + noise: redundant partial reduce (512 quads) -> (std0,std1), then threefry noise.
// element i -> threefry2x32(key=(0,42), ctr=(0,i)), bits = o0^o1
__global__ __launch_bounds__(256) void noise_kernel(float* __restrict__ out,
                                                    const float* __restrict__ partial) {
  int tid = threadIdx.x;
  const float4* pq = (const float4*)partial;  // 512 quads {s0,q0,s1,q1}
  float4 pa = pq[tid];
  float4 pb = pq[tid + 256];
  float s0 = pa.x + pb.x, q0 = pa.y + pb.y, s1 = pa.z + pb.z, q1 = pa.w + pb.w;
  for (int off = 32; off > 0; off >>= 1) {
    s0 += __shfl_down(s0, off);
    q0 += __shfl_down(q0, off);
    s1 += __shfl_down(s1, off);
    q1 += __shfl_down(q1, off);
  }
  __shared__ float red[4][4];
  int wave = tid >> 6;
  if ((tid & 63) == 0) {
    red[wave][0] = s0; red[wave][1] = q0; red[wave][2] = s1; red[wave][3] = q1;
  }
  __syncthreads();
  float S = red[0][0] + red[1][0] + red[2][0] + red[3][0];
  float Q = red[0][1] + red[1][1] + red[2][1] + red[3][1];
  float S2 = red[0][2] + red[1][2] + red[2][2] + red[3][2];
  float Q2 = red[0][3] + red[1][3] + red[2][3] + red[3][3];
  const float invN = 1.0f / 262144.0f;
  float m0 = S * invN, m1 = S2 * invN;
  float std0 = __fsqrt_rn(fmaxf(Q * invN - m0 * m0, 0.0f));
  float std1 = __fsqrt_rn(fmaxf(Q2 * invN - m1 * m1, 0.0f));

  int i = blockIdx.x * 256 + tid;  // < 524288
  uint32_t x0 = 0u;
  uint32_t x1 = (uint32_t)i;
  const uint32_t k0 = 0u, k1 = 42u;
  const uint32_t k2 = k0 ^ k1 ^ 0x1BD11BDAu;
  x0 += k0; x1 += k1;
#define QR(r) x0 += x1; x1 = rotl32(x1, r); x1 ^= x0;
  QR(13) QR(15) QR(26) QR(6)
  x0 += k1; x1 += k2 + 1u;
  QR(17) QR(29) QR(16) QR(24)
  x0 += k2; x1 += k0 + 2u;
  QR(13) QR(15) QR(26) QR(6)
  x0 += k0; x1 += k1 + 3u;
  QR(17) QR(29) QR(16) QR(24)
  x0 += k1; x1 += k2 + 4u;
  QR(13) QR(15) QR(26) QR(6)
  x0 += k2; x1 += k0 + 5u;
#undef QR
  uint32_t bits = x0 ^ x1;
  const float lo = __uint_as_float(0xBF7FFFFFu);  // nextafter(-1,0)
  float f = __uint_as_float((bits >> 9) | 0x3F800000u) - 1.0f;
  float u = fmaxf(lo, __fadd_rn(__fmul_rn(f, 2.0f), lo));
  const float sqrt2 = 1.41421356237309515f;
  out[i] += (i < HALF_N ? std0 : std1) * (sqrt2 * erfinv_xla(u));
}

extern "C" void kernel_launch(void* const* d_in, const int* in_sizes, int n_in,
                              void* d_out, int out_size, void* d_ws, size_t ws_size,
                              hipStream_t stream) {
  const float* x = (const float*)d_in[0];
  float* ws = (float*)d_ws;
  float* Vt      = ws;
  float* partial = ws + 524288;
  float* out = (float*)d_out;

  stageB_kernel<<<512, 512, 0, stream>>>(x, Vt);
  stageC_kernel<<<512, 256, 0, stream>>>(Vt, out, partial);
  noise_kernel<<<2048, 256, 0, stream>>>(out, partial);
}

// Round 11
// 109.911 us; speedup vs baseline: 1.0919x; 1.0093x over previous
//
#include <hip/hip_runtime.h>
#include <stdint.h>
#include <math.h>

// PhysicsForwardModel: B=2, Nz=Nx=128, Ly=Lx=512.
// out[b,t,l] = (1/3) * sum_j Cy[j,l] * sum_k cos(F[k,j]*t) * a[k] * (Cy[:,:128] x[b] Cy[:,128:256]^T)[k,j]
//              + std_b * N(0,1)  (JAX threefry key=42, partitionable counters, XLA erfinv)
// R20: R19 + ONE change: stageB phase C's step cosine cs = cos(64*F[k]) depends only on k,
//      but was recomputed by all 512 threads x 64 kk (32768/block). Hoisted into phase B
//      (1 cos per lane, stored in kq.w; same __cosf(__fmul_rn(F,64)) expr -> bit-identical
//      Vt, zero numeric delta). Phase-C trans work drops 3 -> 2 cos per (k,thread).
//      stageC/noise = R17-verified byte-for-byte.

#define HALF_N 262144  // 512*512 per-batch elements
#define PI_F 3.14159274101257324f

// ws layout (floats): Vt [0..524288) [j][b][t]; partial [524288..526336) 512 x {s0,q0,s1,q1}

__device__ __forceinline__ uint32_t rotl32(uint32_t v, int r) {
  return (v << r) | (v >> (32 - r));
}

// XLA ErfInv32 (Giles) -- matches reference's lax.erf_inv
__device__ __forceinline__ float erfinv_xla(float x) {
  float w = -log1pf(__fmul_rn(-x, x));
  float p;
  if (w < 5.0f) {
    w = w - 2.5f;
    p = 2.81022636e-08f;
    p = fmaf(p, w, 3.43273939e-07f);
    p = fmaf(p, w, -3.5233877e-06f);
    p = fmaf(p, w, -4.39150654e-06f);
    p = fmaf(p, w, 0.00021858087f);
    p = fmaf(p, w, -0.00125372503f);
    p = fmaf(p, w, -0.00417768164f);
    p = fmaf(p, w, 0.246640727f);
    p = fmaf(p, w, 1.50140941f);
  } else {
    w = __fsqrt_rn(w) - 3.0f;
    p = -0.000200214257f;
    p = fmaf(p, w, 0.000100950558f);
    p = fmaf(p, w, 0.00134934322f);
    p = fmaf(p, w, -0.00367342844f);
    p = fmaf(p, w, 0.00573950773f);
    p = fmaf(p, w, -0.0076224613f);
    p = fmaf(p, w, 0.00943887047f);
    p = fmaf(p, w, 1.00167406f);
    p = fmaf(p, w, 2.83297682f);
  }
  return p * x;
}

// Cy[k,n] = sc(k) * 2 * cos(pi*(2n+1)*k/1024), with n2p1 = (float)(2n+1) exact
__device__ __forceinline__ float cy_elem(float n2p1, float kf, float sc) {
  float t1 = __fmul_rn(PI_F, n2p1);
  float arg = __fmul_rn(t1, kf) * (1.0f / 1024.0f);
  return __fmul_rn(sc, __fmul_rn(2.0f, __cosf(arg)));
}

// fusedB, block = j (grid 512, 512 threads):
//   A  (tid<128): cyl[jj] = Cy[j,128+jj]                       [byte-identical math]
//   A2 (tid<256): us[b*128+i] = sum_jj x[b,i,jj]*cyl[jj]       [byte-identical math]
//   B  (lane=k):  kq[k] = {F[k,j], a*acc0, a*acc1, cos(64F)}   [cs hoisted, bit-identical]
//   C  (kg=tid>>6, tg=tid&63): t-octet {tg+64n}, k in [64kg,64kg+64):
//        anchors cos(F*tg), cos(F*(tg+64)) [ref-exact args], step 2*kq.w, recur 6.
__global__ __launch_bounds__(512, 4) void stageB_kernel(const float* __restrict__ x,
                                                        float* __restrict__ Vt) {
  __shared__ float cyl[128];
  __shared__ float us[256];
  __shared__ float4 kq[512];
  __shared__ float red[8][512];
  int j = blockIdx.x;
  int tid = threadIdx.x;
  float jf = (float)j;
  if (tid < 128) {
    float scj = (j == 0) ? (1.0f / __fsqrt_rn(2048.0f)) : 0.03125f;
    cyl[tid] = cy_elem((float)(2 * (128 + tid) + 1), jf, scj);
  }
  __syncthreads();
  if (tid < 256) {
    int b = tid >> 7, i = tid & 127;
    const float* xr = x + (b * 128 + i) * 128;
    float accA = 0.0f, accB = 0.0f;
    for (int jj = 0; jj < 128; jj += 8) {
      float4 xa = *(const float4*)&xr[jj];
      float4 xb = *(const float4*)&xr[jj + 4];
      float4 ca = *(const float4*)&cyl[jj];
      float4 cb = *(const float4*)&cyl[jj + 4];
      accA = fmaf(xa.x, ca.x, accA); accB = fmaf(xa.y, ca.y, accB);
      accA = fmaf(xa.z, ca.z, accA); accB = fmaf(xa.w, ca.w, accB);
      accA = fmaf(xb.x, cb.x, accA); accB = fmaf(xb.y, cb.y, accB);
      accA = fmaf(xb.z, cb.z, accA); accB = fmaf(xb.w, cb.w, accB);
    }
    us[tid] = accA + accB;
  }
  __syncthreads();
  {
    float kf = (float)tid;
    float sc = (tid == 0) ? (1.0f / __fsqrt_rn(2048.0f)) : 0.03125f;
    float a = cy_elem(1.0f, kf, sc);  // i=0: a[k] = Cy[k,0]
    float acc0 = __fmul_rn(a, us[0]);
    float acc1 = __fmul_rn(a, us[128]);
    float accA0 = 0.f, accA1 = 0.f;
    {
      float c1 = cy_elem(3.0f, kf, sc);
      float c2 = cy_elem(5.0f, kf, sc);
      float c3 = cy_elem(7.0f, kf, sc);
      acc0 = fmaf(c1, us[1], acc0);   acc1 = fmaf(c1, us[129], acc1);
      accA0 = fmaf(c2, us[2], accA0); accA1 = fmaf(c2, us[130], accA1);
      acc0 = fmaf(c3, us[3], acc0);   acc1 = fmaf(c3, us[131], acc1);
    }
    for (int i = 4; i < 128; i += 4) {
      float b0 = (float)(2 * i + 1);
      float c0 = cy_elem(b0, kf, sc);
      float c1 = cy_elem(__fadd_rn(b0, 2.0f), kf, sc);
      float c2 = cy_elem(__fadd_rn(b0, 4.0f), kf, sc);
      float c3 = cy_elem(__fadd_rn(b0, 6.0f), kf, sc);
      float4 u0 = *(const float4*)&us[i];
      float4 u1 = *(const float4*)&us[128 + i];
      acc0 = fmaf(c0, u0.x, acc0);   acc1 = fmaf(c0, u1.x, acc1);
      accA0 = fmaf(c1, u0.y, accA0); accA1 = fmaf(c1, u1.y, accA1);
      acc0 = fmaf(c2, u0.z, acc0);   acc1 = fmaf(c2, u1.z, acc1);
      accA0 = fmaf(c3, u0.w, accA0); accA1 = fmaf(c3, u1.w, accA1);
    }
    acc0 += accA0;
    acc1 += accA1;
    const float w0 = PI_F / 512.0f;  // exact pow2 scale of pi_f
    float ky = __fmul_rn(kf, w0);
    float kx = __fmul_rn(jf, w0);
    float fsv = __fsqrt_rn(__fadd_rn(__fmul_rn(ky, ky), __fmul_rn(kx, kx)));
    float cs = __cosf(__fmul_rn(fsv, 64.0f));  // step cosine, hoisted (bit-identical expr)
    kq[tid] = make_float4(fsv, __fmul_rn(a, acc0), __fmul_rn(a, acc1), cs);
  }
  __syncthreads();
  // Phase C: thread (kg, tg); t = tg + 64n (n=0..7); k in [64kg, 64kg+64)
  int kg = tid >> 6, tg = tid & 63;
  int kbeg = kg << 6;
  float tfa = (float)tg;         // anchor t
  float tfb = (float)(tg + 64);  // anchor t + 64
  float a0[8], a1[8];
#pragma unroll
  for (int n = 0; n < 8; ++n) { a0[n] = 0.0f; a1[n] = 0.0f; }
  for (int kk = 0; kk < 64; ++kk) {
    float4 q = kq[kbeg + kk];
    float F = q.x, m0 = q.y, m1 = q.z;
    float k2 = q.w + q.w;  // 2*cos(64F), exact *2
    float ca = __cosf(__fmul_rn(F, tfa));  // bit-matches ref at t = tg
    float cb = __cosf(__fmul_rn(F, tfb));  // bit-matches ref at t = tg+64
    a0[0] = fmaf(ca, m0, a0[0]); a1[0] = fmaf(ca, m1, a1[0]);
    a0[1] = fmaf(cb, m0, a0[1]); a1[1] = fmaf(cb, m1, a1[1]);
#pragma unroll
    for (int n = 2; n < 8; ++n) {
      float cn = fmaf(k2, cb, -ca);
      a0[n] = fmaf(cn, m0, a0[n]); a1[n] = fmaf(cn, m1, a1[n]);
      ca = cb; cb = cn;
    }
  }
  // reduce b0 then b1 across kg (ascending, fixed order); red[kg][t] conflict-free
#pragma unroll
  for (int n = 0; n < 8; ++n) red[kg][(n << 6) + tg] = a0[n];
  __syncthreads();
  float s0 = red[0][tid];
#pragma unroll
  for (int g = 1; g < 8; ++g) s0 += red[g][tid];
  __syncthreads();
#pragma unroll
  for (int n = 0; n < 8; ++n) red[kg][(n << 6) + tg] = a1[n];
  __syncthreads();
  float s1 = red[0][tid];
#pragma unroll
  for (int g = 1; g < 8; ++g) s1 += red[g][tid];
  Vt[(j << 10) + tid] = s0;
  Vt[(j << 10) + 512 + tid] = s1;
}

// stageC: R17-verified byte-for-byte. block = (t-pair, l-half) (grid 512, 256 threads).
// Chebyshev coefficient recurrence with __cosf anchors every 16 j (ref-exact anchor args);
// raw-cos accumulation, single exact *0.0625, then /3.
__global__ __launch_bounds__(256, 4) void stageC_kernel(const float* __restrict__ Vt,
                                                        float* __restrict__ out,
                                                        float* __restrict__ partial) {
  __shared__ float vq[2048];  // [j][4] = {b0t0, b1t0, b0t1, b1t1}
  int tpair = blockIdx.x >> 1;
  int lhalf = blockIdx.x & 1;
  int t0 = tpair << 1;
  int tid = threadIdx.x;
#pragma unroll
  for (int r = 0; r < 2; ++r) {
    int j = tid + (r << 8);
    const float* base = Vt + (j << 10);
    vq[(j << 2) + 0] = base[t0];
    vq[(j << 2) + 1] = base[512 + t0];
    vq[(j << 2) + 2] = base[t0 + 1];
    vq[(j << 2) + 3] = base[512 + t0 + 1];
  }
  __syncthreads();
  int l = (lhalf << 8) + tid;
  float t1 = __fmul_rn(PI_F, (float)(2 * l + 1));
  float cth = __cosf(__fmul_rn(t1, 1.0f) * (1.0f / 1024.0f));
  float k2 = cth + cth;  // exact *2
  float cy0 = __fmul_rn(1.0f / __fsqrt_rn(2048.0f), 2.0f);
  float c16 = __fmul_rn(cy0, 16.0f);
  float4 v0 = *(const float4*)&vq[0];
  float a00 = __fmul_rn(c16, v0.x);
  float a01 = __fmul_rn(c16, v0.y);
  float a10 = __fmul_rn(c16, v0.z);
  float a11 = __fmul_rn(c16, v0.w);
  float c_m1, c_m2;
  {
    float4 v1 = *(const float4*)&vq[1 << 2];
    a00 = fmaf(cth, v1.x, a00); a01 = fmaf(cth, v1.y, a01);
    a10 = fmaf(cth, v1.z, a10); a11 = fmaf(cth, v1.w, a11);
    float c2v = __cosf(__fmul_rn(t1, 2.0f) * (1.0f / 1024.0f));
    float4 v2 = *(const float4*)&vq[2 << 2];
    a00 = fmaf(c2v, v2.x, a00); a01 = fmaf(c2v, v2.y, a01);
    a10 = fmaf(c2v, v2.z, a10); a11 = fmaf(c2v, v2.w, a11);
    c_m2 = cth; c_m1 = c2v;
#pragma unroll
    for (int j = 3; j < 16; ++j) {
      float cn = fmaf(k2, c_m1, -c_m2);
      float4 v = *(const float4*)&vq[j << 2];
      a00 = fmaf(cn, v.x, a00); a01 = fmaf(cn, v.y, a01);
      a10 = fmaf(cn, v.z, a10); a11 = fmaf(cn, v.w, a11);
      c_m2 = c_m1; c_m1 = cn;
    }
  }
  for (int j0 = 16; j0 < 512; j0 += 16) {
    float jb = (float)j0;
    float ca = __cosf(__fmul_rn(t1, jb) * (1.0f / 1024.0f));
    float cb = __cosf(__fmul_rn(t1, __fadd_rn(jb, 1.0f)) * (1.0f / 1024.0f));
    float4 va = *(const float4*)&vq[j0 << 2];
    a00 = fmaf(ca, va.x, a00); a01 = fmaf(ca, va.y, a01);
    a10 = fmaf(ca, va.z, a10); a11 = fmaf(ca, va.w, a11);
    float4 vb = *(const float4*)&vq[(j0 + 1) << 2];
    a00 = fmaf(cb, vb.x, a00); a01 = fmaf(cb, vb.y, a01);
    a10 = fmaf(cb, vb.z, a10); a11 = fmaf(cb, vb.w, a11);
    c_m2 = ca; c_m1 = cb;
#pragma unroll
    for (int n = 2; n < 16; ++n) {
      float cn = fmaf(k2, c_m1, -c_m2);
      float4 v = *(const float4*)&vq[(j0 + n) << 2];
      a00 = fmaf(cn, v.x, a00); a01 = fmaf(cn, v.y, a01);
      a10 = fmaf(cn, v.z, a10); a11 = fmaf(cn, v.w, a11);
      c_m2 = c_m1; c_m1 = cn;
    }
  }
  float p00 = __fmul_rn(a00, 0.0625f) / 3.0f;
  float p01 = __fmul_rn(a01, 0.0625f) / 3.0f;
  float p10 = __fmul_rn(a10, 0.0625f) / 3.0f;
  float p11 = __fmul_rn(a11, 0.0625f) / 3.0f;
  out[(t0 << 9) + l] = p00;
  out[((t0 + 1) << 9) + l] = p10;
  out[HALF_N + (t0 << 9) + l] = p01;
  out[HALF_N + ((t0 + 1) << 9) + l] = p11;
  float s0 = p00 + p10, q0 = fmaf(p00, p00, p10 * p10);
  float s1 = p01 + p11, q1 = fmaf(p01, p01, p11 * p11);
  for (int off = 32; off > 0; off >>= 1) {
    s0 += __shfl_down(s0, off);
    q0 += __shfl_down(q0, off);
    s1 += __shfl_down(s1, off);
    q1 += __shfl_down(q1, off);
  }
  __shared__ float red[4][4];
  int wave = tid >> 6;
  if ((tid & 63) == 0) {
    red[wave][0] = s0; red[wave][1] = q0; red[wave][2] = s1; red[wave][3] = q1;
  }
  __syncthreads();
  if (tid == 0) {
    float a0 = 0.f, a1 = 0.f, a2 = 0.f, a3 = 0.f;
    for (int wv = 0; wv < 4; ++wv) {
      a0 += red[wv][0]; a1 += red[wv][1]; a2 += red[wv][2]; a3 += red[wv][3];
    }
    partial[blockIdx.x * 4 + 0] = a0;
    partial[blockIdx.x * 4 + 1] = a1;
    partial[blockIdx.x * 4 + 2] = a2;
    partial[blockIdx.x * 4 + 3] = a3;
  }
}

// Fused stats + noise: redundant partial reduce (512 quads) -> (std0,std1), then threefry noise.
// element i -> threefry2x32(key=(0,42), ctr=(0,i)), bits = o0^o1
__global__ __launch_bounds__(256) void noise_kernel(float* __restrict__ out,
                                                    const float* __restrict__ partial) {
  int tid = threadIdx.x;
  const float4* pq = (const float4*)partial;  // 512 quads {s0,q0,s1,q1}
  float4 pa = pq[tid];
  float4 pb = pq[tid + 256];
  float s0 = pa.x + pb.x, q0 = pa.y + pb.y, s1 = pa.z + pb.z, q1 = pa.w + pb.w;
  for (int off = 32; off > 0; off >>= 1) {
    s0 += __shfl_down(s0, off);
    q0 += __shfl_down(q0, off);
    s1 += __shfl_down(s1, off);
    q1 += __shfl_down(q1, off);
  }
  __shared__ float red[4][4];
  int wave = tid >> 6;
  if ((tid & 63) == 0) {
    red[wave][0] = s0; red[wave][1] = q0; red[wave][2] = s1; red[wave][3] = q1;
  }
  __syncthreads();
  float S = red[0][0] + red[1][0] + red[2][0] + red[3][0];
  float Q = red[0][1] + red[1][1] + red[2][1] + red[3][1];
  float S2 = red[0][2] + red[1][2] + red[2][2] + red[3][2];
  float Q2 = red[0][3] + red[1][3] + red[2][3] + red[3][3];
  const float invN = 1.0f / 262144.0f;
  float m0 = S * invN, m1 = S2 * invN;
  float std0 = __fsqrt_rn(fmaxf(Q * invN - m0 * m0, 0.0f));
  float std1 = __fsqrt_rn(fmaxf(Q2 * invN - m1 * m1, 0.0f));

  int i = blockIdx.x * 256 + tid;  // < 524288
  uint32_t x0 = 0u;
  uint32_t x1 = (uint32_t)i;
  const uint32_t k0 = 0u, k1 = 42u;
  const uint32_t k2 = k0 ^ k1 ^ 0x1BD11BDAu;
  x0 += k0; x1 += k1;
#define QR(r) x0 += x1; x1 = rotl32(x1, r); x1 ^= x0;
  QR(13) QR(15) QR(26) QR(6)
  x0 += k1; x1 += k2 + 1u;
  QR(17) QR(29) QR(16) QR(24)
  x0 += k2; x1 += k0 + 2u;
  QR(13) QR(15) QR(26) QR(6)
  x0 += k0; x1 += k1 + 3u;
  QR(17) QR(29) QR(16) QR(24)
  x0 += k1; x1 += k2 + 4u;
  QR(13) QR(15) QR(26) QR(6)
  x0 += k2; x1 += k0 + 5u;
#undef QR
  uint32_t bits = x0 ^ x1;
  const float lo = __uint_as_float(0xBF7FFFFFu);  // nextafter(-1,0)
  float f = __uint_as_float((bits >> 9) | 0x3F800000u) - 1.0f;
  float u = fmaxf(lo, __fadd_rn(__fmul_rn(f, 2.0f), lo));
  const float sqrt2 = 1.41421356237309515f;
  out[i] += (i < HALF_N ? std0 : std1) * (sqrt2 * erfinv_xla(u));
}

extern "C" void kernel_launch(void* const* d_in, const int* in_sizes, int n_in,
                              void* d_out, int out_size, void* d_ws, size_t ws_size,
                              hipStream_t stream) {
  const float* x = (const float*)d_in[0];
  float* ws = (float*)d_ws;
  float* Vt      = ws;
  float* partial = ws + 524288;
  float* out = (float*)d_out;

  stageB_kernel<<<512, 512, 0, stream>>>(x, Vt);
  stageC_kernel<<<512, 256, 0, stream>>>(Vt, out, partial);
  noise_kernel<<<2048, 256, 0, stream>>>(out, partial);
}

// Round 12
// 102.707 us; speedup vs baseline: 1.1684x; 1.0701x over previous
//
#include <hip/hip_runtime.h>
#include <stdint.h>
#include <math.h>

// PhysicsForwardModel: B=2, Nz=Nx=128, Ly=Lx=512.
// out[b,t,l] = (1/3) * sum_j Cy[j,l] * sum_k cos(F[k,j]*t) * a[k] * (Cy[:,:128] x[b] Cy[:,128:256]^T)[k,j]
//              + std_b * N(0,1)  (JAX threefry key=42, partitionable counters, XLA erfinv)
// R21: stageB/noise = R20 byte-for-byte. stageC exploits DCT parity symmetry
//      C[j,511-l] = (-1)^j C[j,l]: thread keeps even-j (E) and odd-j (O) sums ->
//      out[t,l] = (E+O)*s, out[t,511-l] = (E-O)*s. Same per-j LDS read + fma count,
//      2x outputs => stageC's per-CU LDS-broadcast work halves. Block = one t (grid 512,
//      256 thr, 2 blocks/CU), vq[j][2] b64 broadcasts, R17-class Chebyshev coefficient
//      recurrence (identical anchor exprs -> identical coefficient values).

#define HALF_N 262144  // 512*512 per-batch elements
#define PI_F 3.14159274101257324f

// ws layout (floats): Vt [0..524288) [j][b][t]; partial [524288..526336) 512 x {s0,q0,s1,q1}

__device__ __forceinline__ uint32_t rotl32(uint32_t v, int r) {
  return (v << r) | (v >> (32 - r));
}

// XLA ErfInv32 (Giles) -- matches reference's lax.erf_inv
__device__ __forceinline__ float erfinv_xla(float x) {
  float w = -log1pf(__fmul_rn(-x, x));
  float p;
  if (w < 5.0f) {
    w = w - 2.5f;
    p = 2.81022636e-08f;
    p = fmaf(p, w, 3.43273939e-07f);
    p = fmaf(p, w, -3.5233877e-06f);
    p = fmaf(p, w, -4.39150654e-06f);
    p = fmaf(p, w, 0.00021858087f);
    p = fmaf(p, w, -0.00125372503f);
    p = fmaf(p, w, -0.00417768164f);
    p = fmaf(p, w, 0.246640727f);
    p = fmaf(p, w, 1.50140941f);
  } else {
    w = __fsqrt_rn(w) - 3.0f;
    p = -0.000200214257f;
    p = fmaf(p, w, 0.000100950558f);
    p = fmaf(p, w, 0.00134934322f);
    p = fmaf(p, w, -0.00367342844f);
    p = fmaf(p, w, 0.00573950773f);
    p = fmaf(p, w, -0.0076224613f);
    p = fmaf(p, w, 0.00943887047f);
    p = fmaf(p, w, 1.00167406f);
    p = fmaf(p, w, 2.83297682f);
  }
  return p * x;
}

// Cy[k,n] = sc(k) * 2 * cos(pi*(2n+1)*k/1024), with n2p1 = (float)(2n+1) exact
__device__ __forceinline__ float cy_elem(float n2p1, float kf, float sc) {
  float t1 = __fmul_rn(PI_F, n2p1);
  float arg = __fmul_rn(t1, kf) * (1.0f / 1024.0f);
  return __fmul_rn(sc, __fmul_rn(2.0f, __cosf(arg)));
}

// fusedB, block = j (grid 512, 512 threads):  [R20-verified, byte-identical]
__global__ __launch_bounds__(512, 4) void stageB_kernel(const float* __restrict__ x,
                                                        float* __restrict__ Vt) {
  __shared__ float cyl[128];
  __shared__ float us[256];
  __shared__ float4 kq[512];
  __shared__ float red[8][512];
  int j = blockIdx.x;
  int tid = threadIdx.x;
  float jf = (float)j;
  if (tid < 128) {
    float scj = (j == 0) ? (1.0f / __fsqrt_rn(2048.0f)) : 0.03125f;
    cyl[tid] = cy_elem((float)(2 * (128 + tid) + 1), jf, scj);
  }
  __syncthreads();
  if (tid < 256) {
    int b = tid >> 7, i = tid & 127;
    const float* xr = x + (b * 128 + i) * 128;
    float accA = 0.0f, accB = 0.0f;
    for (int jj = 0; jj < 128; jj += 8) {
      float4 xa = *(const float4*)&xr[jj];
      float4 xb = *(const float4*)&xr[jj + 4];
      float4 ca = *(const float4*)&cyl[jj];
      float4 cb = *(const float4*)&cyl[jj + 4];
      accA = fmaf(xa.x, ca.x, accA); accB = fmaf(xa.y, ca.y, accB);
      accA = fmaf(xa.z, ca.z, accA); accB = fmaf(xa.w, ca.w, accB);
      accA = fmaf(xb.x, cb.x, accA); accB = fmaf(xb.y, cb.y, accB);
      accA = fmaf(xb.z, cb.z, accA); accB = fmaf(xb.w, cb.w, accB);
    }
    us[tid] = accA + accB;
  }
  __syncthreads();
  {
    float kf = (float)tid;
    float sc = (tid == 0) ? (1.0f / __fsqrt_rn(2048.0f)) : 0.03125f;
    float a = cy_elem(1.0f, kf, sc);  // i=0: a[k] = Cy[k,0]
    float acc0 = __fmul_rn(a, us[0]);
    float acc1 = __fmul_rn(a, us[128]);
    float accA0 = 0.f, accA1 = 0.f;
    {
      float c1 = cy_elem(3.0f, kf, sc);
      float c2 = cy_elem(5.0f, kf, sc);
      float c3 = cy_elem(7.0f, kf, sc);
      acc0 = fmaf(c1, us[1], acc0);   acc1 = fmaf(c1, us[129], acc1);
      accA0 = fmaf(c2, us[2], accA0); accA1 = fmaf(c2, us[130], accA1);
      acc0 = fmaf(c3, us[3], acc0);   acc1 = fmaf(c3, us[131], acc1);
    }
    for (int i = 4; i < 128; i += 4) {
      float b0 = (float)(2 * i + 1);
      float c0 = cy_elem(b0, kf, sc);
      float c1 = cy_elem(__fadd_rn(b0, 2.0f), kf, sc);
      float c2 = cy_elem(__fadd_rn(b0, 4.0f), kf, sc);
      float c3 = cy_elem(__fadd_rn(b0, 6.0f), kf, sc);
      float4 u0 = *(const float4*)&us[i];
      float4 u1 = *(const float4*)&us[128 + i];
      acc0 = fmaf(c0, u0.x, acc0);   acc1 = fmaf(c0, u1.x, acc1);
      accA0 = fmaf(c1, u0.y, accA0); accA1 = fmaf(c1, u1.y, accA1);
      acc0 = fmaf(c2, u0.z, acc0);   acc1 = fmaf(c2, u1.z, acc1);
      accA0 = fmaf(c3, u0.w, accA0); accA1 = fmaf(c3, u1.w, accA1);
    }
    acc0 += accA0;
    acc1 += accA1;
    const float w0 = PI_F / 512.0f;  // exact pow2 scale of pi_f
    float ky = __fmul_rn(kf, w0);
    float kx = __fmul_rn(jf, w0);
    float fsv = __fsqrt_rn(__fadd_rn(__fmul_rn(ky, ky), __fmul_rn(kx, kx)));
    float cs = __cosf(__fmul_rn(fsv, 64.0f));  // step cosine, hoisted (bit-identical expr)
    kq[tid] = make_float4(fsv, __fmul_rn(a, acc0), __fmul_rn(a, acc1), cs);
  }
  __syncthreads();
  // Phase C: thread (kg, tg); t = tg + 64n (n=0..7); k in [64kg, 64kg+64)
  int kg = tid >> 6, tg = tid & 63;
  int kbeg = kg << 6;
  float tfa = (float)tg;         // anchor t
  float tfb = (float)(tg + 64);  // anchor t + 64
  float a0[8], a1[8];
#pragma unroll
  for (int n = 0; n < 8; ++n) { a0[n] = 0.0f; a1[n] = 0.0f; }
  for (int kk = 0; kk < 64; ++kk) {
    float4 q = kq[kbeg + kk];
    float F = q.x, m0 = q.y, m1 = q.z;
    float k2 = q.w + q.w;  // 2*cos(64F), exact *2
    float ca = __cosf(__fmul_rn(F, tfa));  // bit-matches ref at t = tg
    float cb = __cosf(__fmul_rn(F, tfb));  // bit-matches ref at t = tg+64
    a0[0] = fmaf(ca, m0, a0[0]); a1[0] = fmaf(ca, m1, a1[0]);
    a0[1] = fmaf(cb, m0, a0[1]); a1[1] = fmaf(cb, m1, a1[1]);
#pragma unroll
    for (int n = 2; n < 8; ++n) {
      float cn = fmaf(k2, cb, -ca);
      a0[n] = fmaf(cn, m0, a0[n]); a1[n] = fmaf(cn, m1, a1[n]);
      ca = cb; cb = cn;
    }
  }
  // reduce b0 then b1 across kg (ascending, fixed order); red[kg][t] conflict-free
#pragma unroll
  for (int n = 0; n < 8; ++n) red[kg][(n << 6) + tg] = a0[n];
  __syncthreads();
  float s0 = red[0][tid];
#pragma unroll
  for (int g = 1; g < 8; ++g) s0 += red[g][tid];
  __syncthreads();
#pragma unroll
  for (int n = 0; n < 8; ++n) red[kg][(n << 6) + tg] = a1[n];
  __syncthreads();
  float s1 = red[0][tid];
#pragma unroll
  for (int g = 1; g < 8; ++g) s1 += red[g][tid];
  Vt[(j << 10) + tid] = s0;
  Vt[(j << 10) + 512 + tid] = s1;
}

// stageC v5 (parity-symmetric): block = t (grid 512, 256 threads), lane l in [0,256).
//   E = sum_{even j} c_j v_j, O = sum_{odd j} c_j v_j (raw cos, R17-identical coefficients
//   via Chebyshev recurrence + anchors); out[t,l] = (E+O)*0.0625/3,
//   out[t,511-l] = (E-O)*0.0625/3  (C[j,511-l] = (-1)^j C[j,l] up to coefficient ulp).
__global__ __launch_bounds__(256, 4) void stageC_kernel(const float* __restrict__ Vt,
                                                        float* __restrict__ out,
                                                        float* __restrict__ partial) {
  __shared__ float vq[1024];  // [j][2] = {b0, b1} for this block's t
  int t = blockIdx.x;
  int tid = threadIdx.x;
  {
    const float* b0p = Vt + (tid << 10);
    const float* b1p = b0p + 512;
    vq[2 * tid] = b0p[t];
    vq[2 * tid + 1] = b1p[t];
    const float* b0q = Vt + ((tid + 256) << 10);
    const float* b1q = b0q + 512;
    vq[2 * tid + 512] = b0q[t];
    vq[2 * tid + 513] = b1q[t];
  }
  __syncthreads();
  int l = tid;
  float t1 = __fmul_rn(PI_F, (float)(2 * l + 1));
  float cth = __cosf(__fmul_rn(t1, 1.0f) * (1.0f / 1024.0f));
  float k2 = cth + cth;  // exact *2
  float cy0 = __fmul_rn(1.0f / __fsqrt_rn(2048.0f), 2.0f);
  float c16 = __fmul_rn(cy0, 16.0f);
  // E (even j) and O (odd j) accumulators, raw-cos scale x16 undone at the end
  float e0, e1, o0, o1;
  float c_m1, c_m2;
  {
    float2 v0 = *(const float2*)&vq[0];
    e0 = __fmul_rn(c16, v0.x);
    e1 = __fmul_rn(c16, v0.y);
    float2 v1 = *(const float2*)&vq[2];
    o0 = __fmul_rn(cth, v1.x);
    o1 = __fmul_rn(cth, v1.y);
    float c2v = __cosf(__fmul_rn(t1, 2.0f) * (1.0f / 1024.0f));
    float2 v2 = *(const float2*)&vq[4];
    e0 = fmaf(c2v, v2.x, e0); e1 = fmaf(c2v, v2.y, e1);
    c_m2 = cth; c_m1 = c2v;
#pragma unroll
    for (int j = 3; j < 16; ++j) {
      float cn = fmaf(k2, c_m1, -c_m2);
      float2 v = *(const float2*)&vq[j << 1];
      if (j & 1) { o0 = fmaf(cn, v.x, o0); o1 = fmaf(cn, v.y, o1); }
      else       { e0 = fmaf(cn, v.x, e0); e1 = fmaf(cn, v.y, e1); }
      c_m2 = c_m1; c_m1 = cn;
    }
  }
  for (int j0 = 16; j0 < 512; j0 += 16) {
    float jb = (float)j0;
    float ca = __cosf(__fmul_rn(t1, jb) * (1.0f / 1024.0f));                      // even
    float cb = __cosf(__fmul_rn(t1, __fadd_rn(jb, 1.0f)) * (1.0f / 1024.0f));    // odd
    float2 va = *(const float2*)&vq[j0 << 1];
    e0 = fmaf(ca, va.x, e0); e1 = fmaf(ca, va.y, e1);
    float2 vb = *(const float2*)&vq[(j0 + 1) << 1];
    o0 = fmaf(cb, vb.x, o0); o1 = fmaf(cb, vb.y, o1);
    c_m2 = ca; c_m1 = cb;
#pragma unroll
    for (int n = 2; n < 16; ++n) {
      float cn = fmaf(k2, c_m1, -c_m2);
      float2 v = *(const float2*)&vq[(j0 + n) << 1];
      if (n & 1) { o0 = fmaf(cn, v.x, o0); o1 = fmaf(cn, v.y, o1); }
      else       { e0 = fmaf(cn, v.x, e0); e1 = fmaf(cn, v.y, e1); }
      c_m2 = c_m1; c_m1 = cn;
    }
  }
  // combine: l gets E+O, 511-l gets E-O; exact pow2 rescale then /3
  float pA0 = __fmul_rn(e0 + o0, 0.0625f) / 3.0f;  // (t, l, b0)
  float pA1 = __fmul_rn(e1 + o1, 0.0625f) / 3.0f;  // (t, l, b1)
  float pB0 = __fmul_rn(e0 - o0, 0.0625f) / 3.0f;  // (t, 511-l, b0)
  float pB1 = __fmul_rn(e1 - o1, 0.0625f) / 3.0f;  // (t, 511-l, b1)
  int lr = 511 - l;
  out[(t << 9) + l] = pA0;
  out[HALF_N + (t << 9) + l] = pA1;
  out[(t << 9) + lr] = pB0;
  out[HALF_N + (t << 9) + lr] = pB1;
  // stats partials (regrouped -- verified-safe class)
  float s0 = pA0 + pB0, q0 = fmaf(pA0, pA0, pB0 * pB0);
  float s1 = pA1 + pB1, q1 = fmaf(pA1, pA1, pB1 * pB1);
  for (int off = 32; off > 0; off >>= 1) {
    s0 += __shfl_down(s0, off);
    q0 += __shfl_down(q0, off);
    s1 += __shfl_down(s1, off);
    q1 += __shfl_down(q1, off);
  }
  __shared__ float red[4][4];
  int wave = tid >> 6;
  if ((tid & 63) == 0) {
    red[wave][0] = s0; red[wave][1] = q0; red[wave][2] = s1; red[wave][3] = q1;
  }
  __syncthreads();
  if (tid == 0) {
    float a0 = 0.f, a1 = 0.f, a2 = 0.f, a3 = 0.f;
    for (int wv = 0; wv < 4; ++wv) {
      a0 += red[wv][0]; a1 += red[wv][1]; a2 += red[wv][2]; a3 += red[wv][3];
    }
    partial[blockIdx.x * 4 + 0] = a0;
    partial[blockIdx.x * 4 + 1] = a1;
    partial[blockIdx.x * 4 + 2] = a2;
    partial[blockIdx.x * 4 + 3] = a3;
  }
}

// Fused stats + noise: redundant partial reduce (512 quads) -> (std0,std1), then threefry noise.
// element i -> threefry2x32(key=(0,42), ctr=(0,i)), bits = o0^o1
__global__ __launch_bounds__(256) void noise_kernel(float* __restrict__ out,
                                                    const float* __restrict__ partial) {
  int tid = threadIdx.x;
  const float4* pq = (const float4*)partial;  // 512 quads {s0,q0,s1,q1}
  float4 pa = pq[tid];
  float4 pb = pq[tid + 256];
  float s0 = pa.x + pb.x, q0 = pa.y + pb.y, s1 = pa.z + pb.z, q1 = pa.w + pb.w;
  for (int off = 32; off > 0; off >>= 1) {
    s0 += __shfl_down(s0, off);
    q0 += __shfl_down(q0, off);
    s1 += __shfl_down(s1, off);
    q1 += __shfl_down(q1, off);
  }
  __shared__ float red[4][4];
  int wave = tid >> 6;
  if ((tid & 63) == 0) {
    red[wave][0] = s0; red[wave][1] = q0; red[wave][2] = s1; red[wave][3] = q1;
  }
  __syncthreads();
  float S = red[0][0] + red[1][0] + red[2][0] + red[3][0];
  float Q = red[0][1] + red[1][1] + red[2][1] + red[3][1];
  float S2 = red[0][2] + red[1][2] + red[2][2] + red[3][2];
  float Q2 = red[0][3] + red[1][3] + red[2][3] + red[3][3];
  const float invN = 1.0f / 262144.0f;
  float m0 = S * invN, m1 = S2 * invN;
  float std0 = __fsqrt_rn(fmaxf(Q * invN - m0 * m0, 0.0f));
  float std1 = __fsqrt_rn(fmaxf(Q2 * invN - m1 * m1, 0.0f));

  int i = blockIdx.x * 256 + tid;  // < 524288
  uint32_t x0 = 0u;
  uint32_t x1 = (uint32_t)i;
  const uint32_t k0 = 0u, k1 = 42u;
  const uint32_t k2 = k0 ^ k1 ^ 0x1BD11BDAu;
  x0 += k0; x1 += k1;
#define QR(r) x0 += x1; x1 = rotl32(x1, r); x1 ^= x0;
  QR(13) QR(15) QR(26) QR(6)
  x0 += k1; x1 += k2 + 1u;
  QR(17) QR(29) QR(16) QR(24)
  x0 += k2; x1 += k0 + 2u;
  QR(13) QR(15) QR(26) QR(6)
  x0 += k0; x1 += k1 + 3u;
  QR(17) QR(29) QR(16) QR(24)
  x0 += k1; x1 += k2 + 4u;
  QR(13) QR(15) QR(26) QR(6)
  x0 += k2; x1 += k0 + 5u;
#undef QR
  uint32_t bits = x0 ^ x1;
  const float lo = __uint_as_float(0xBF7FFFFFu);  // nextafter(-1,0)
  float f = __uint_as_float((bits >> 9) | 0x3F800000u) - 1.0f;
  float u = fmaxf(lo, __fadd_rn(__fmul_rn(f, 2.0f), lo));
  const float sqrt2 = 1.41421356237309515f;
  out[i] += (i < HALF_N ? std0 : std1) * (sqrt2 * erfinv_xla(u));
}

extern "C" void kernel_launch(void* const* d_in, const int* in_sizes, int n_in,
                              void* d_out, int out_size, void* d_ws, size_t ws_size,
                              hipStream_t stream) {
  const float* x = (const float*)d_in[0];
  float* ws = (float*)d_ws;
  float* Vt      = ws;
  float* partial = ws + 524288;
  float* out = (float*)d_out;

  stageB_kernel<<<512, 512, 0, stream>>>(x, Vt);
  stageC_kernel<<<512, 256, 0, stream>>>(Vt, out, partial);
  noise_kernel<<<2048, 256, 0, stream>>>(out, partial);
}

// Round 13
// 97.293 us; speedup vs baseline: 1.2335x; 1.0556x over previous
//
#include <hip/hip_runtime.h>
#include <stdint.h>
#include <math.h>

// PhysicsForwardModel: B=2, Nz=Nx=128, Ly=Lx=512.
// out[b,t,l] = (1/3) * sum_j Cy[j,l] * sum_k cos(F[k,j]*t) * a[k] * (Cy[:,:128] x[b] Cy[:,128:256]^T)[k,j]
//              + std_b * N(0,1)  (JAX threefry key=42, partitionable counters, XLA erfinv)
// R22: stageC/noise = R21 byte-for-byte. stageB gets the validated Chebyshev treatment on
//      both remaining cos loops:
//      - phase B: coefficient arg pi*k*(2i+1)/1024 is linear in i -> recurrence with step
//        2*cos(pi*k/512), cy_elem-exact anchors every 16 i (R1's exact exprs). 128 -> 17
//        cos/thread and ~640 -> ~200 arg-VALU/thread. R1 chain order preserved exactly.
//      - phase C: t-recurrence deepened 8 -> 16 (kg 16 x tg 32; anchors cos(F*tg),
//        cos(F*(tg+32)) ref-exact; step cos(32F) hoisted in kq.w; recur 14 = verified depth).
//        128 -> 64 cos/thread. red[16][512] reduction conflict-free (2-way = free).

#define HALF_N 262144  // 512*512 per-batch elements
#define PI_F 3.14159274101257324f

// ws layout (floats): Vt [0..524288) [j][b][t]; partial [524288..526336) 512 x {s0,q0,s1,q1}

__device__ __forceinline__ uint32_t rotl32(uint32_t v, int r) {
  return (v << r) | (v >> (32 - r));
}

// XLA ErfInv32 (Giles) -- matches reference's lax.erf_inv
__device__ __forceinline__ float erfinv_xla(float x) {
  float w = -log1pf(__fmul_rn(-x, x));
  float p;
  if (w < 5.0f) {
    w = w - 2.5f;
    p = 2.81022636e-08f;
    p = fmaf(p, w, 3.43273939e-07f);
    p = fmaf(p, w, -3.5233877e-06f);
    p = fmaf(p, w, -4.39150654e-06f);
    p = fmaf(p, w, 0.00021858087f);
    p = fmaf(p, w, -0.00125372503f);
    p = fmaf(p, w, -0.00417768164f);
    p = fmaf(p, w, 0.246640727f);
    p = fmaf(p, w, 1.50140941f);
  } else {
    w = __fsqrt_rn(w) - 3.0f;
    p = -0.000200214257f;
    p = fmaf(p, w, 0.000100950558f);
    p = fmaf(p, w, 0.00134934322f);
    p = fmaf(p, w, -0.00367342844f);
    p = fmaf(p, w, 0.00573950773f);
    p = fmaf(p, w, -0.0076224613f);
    p = fmaf(p, w, 0.00943887047f);
    p = fmaf(p, w, 1.00167406f);
    p = fmaf(p, w, 2.83297682f);
  }
  return p * x;
}

// Cy[k,n] = sc(k) * 2 * cos(pi*(2n+1)*k/1024), with n2p1 = (float)(2n+1) exact
__device__ __forceinline__ float cy_elem(float n2p1, float kf, float sc) {
  float t1 = __fmul_rn(PI_F, n2p1);
  float arg = __fmul_rn(t1, kf) * (1.0f / 1024.0f);
  return __fmul_rn(sc, __fmul_rn(2.0f, __cosf(arg)));
}

// fusedB, block = j (grid 512, 512 threads):
//   A  (tid<128): cyl[jj] = Cy[j,128+jj]                       [byte-identical math]
//   A2 (tid<256): us[b*128+i] = sum_jj x[b,i,jj]*cyl[jj]       [byte-identical math]
//   B  (lane=k):  Chebyshev-recurred coefficients (anchors every 16 i, R1-exact exprs);
//                 kq[k] = {F[k,j], a*acc0, a*acc1, cos(32F)}
//   C  (kg=tid>>5, tg=tid&31): 16 t's {tg+32n}, k in [32kg,32kg+32):
//        anchors cos(F*tg), cos(F*(tg+32)) [ref-exact args], step 2*kq.w, recur 14.
__global__ __launch_bounds__(512, 4) void stageB_kernel(const float* __restrict__ x,
                                                        float* __restrict__ Vt) {
  __shared__ float cyl[128];
  __shared__ float us[256];
  __shared__ float4 kq[512];
  __shared__ float red[16][512];
  int j = blockIdx.x;
  int tid = threadIdx.x;
  float jf = (float)j;
  if (tid < 128) {
    float scj = (j == 0) ? (1.0f / __fsqrt_rn(2048.0f)) : 0.03125f;
    cyl[tid] = cy_elem((float)(2 * (128 + tid) + 1), jf, scj);
  }
  __syncthreads();
  if (tid < 256) {
    int b = tid >> 7, i = tid & 127;
    const float* xr = x + (b * 128 + i) * 128;
    float accA = 0.0f, accB = 0.0f;
    for (int jj = 0; jj < 128; jj += 8) {
      float4 xa = *(const float4*)&xr[jj];
      float4 xb = *(const float4*)&xr[jj + 4];
      float4 ca = *(const float4*)&cyl[jj];
      float4 cb = *(const float4*)&cyl[jj + 4];
      accA = fmaf(xa.x, ca.x, accA); accB = fmaf(xa.y, ca.y, accB);
      accA = fmaf(xa.z, ca.z, accA); accB = fmaf(xa.w, ca.w, accB);
      accA = fmaf(xb.x, cb.x, accA); accB = fmaf(xb.y, cb.y, accB);
      accA = fmaf(xb.z, cb.z, accA); accB = fmaf(xb.w, cb.w, accB);
    }
    us[tid] = accA + accB;
  }
  __syncthreads();
  {
    float kf = (float)tid;
    float sc = (tid == 0) ? (1.0f / __fsqrt_rn(2048.0f)) : 0.03125f;
    // coefficient recurrence step: 2*cos(pi*k/512)  (PI_F/512 exact pow2 scale)
    float thc = __cosf(__fmul_rn(kf, PI_F / 512.0f));
    float k2b = thc + thc;  // exact *2
    float a = cy_elem(1.0f, kf, sc);   // i=0 anchor (bit-identical)
    float c1 = cy_elem(3.0f, kf, sc);  // i=1 anchor (bit-identical)
    float acc0 = __fmul_rn(a, us[0]);
    float acc1 = __fmul_rn(a, us[128]);
    float accA0 = 0.f, accA1 = 0.f;
    acc0 = fmaf(c1, us[1], acc0);   acc1 = fmaf(c1, us[129], acc1);
    float cc2 = fmaf(k2b, c1, -a);      // i=2 (recurred)
    accA0 = fmaf(cc2, us[2], accA0); accA1 = fmaf(cc2, us[130], accA1);
    float cc3 = fmaf(k2b, cc2, -c1);    // i=3
    acc0 = fmaf(cc3, us[3], acc0);   acc1 = fmaf(cc3, us[131], acc1);
    float cm2 = cc2, cm1 = cc3;
#pragma unroll
    for (int q = 1; q < 4; ++q) {  // i = 4..15
      int i = q << 2;
      float4 v0 = *(const float4*)&us[i];
      float4 v1 = *(const float4*)&us[128 + i];
      float d0 = fmaf(k2b, cm1, -cm2);
      acc0 = fmaf(d0, v0.x, acc0);   acc1 = fmaf(d0, v1.x, acc1);
      float d1 = fmaf(k2b, d0, -cm1);
      accA0 = fmaf(d1, v0.y, accA0); accA1 = fmaf(d1, v1.y, accA1);
      float d2 = fmaf(k2b, d1, -d0);
      acc0 = fmaf(d2, v0.z, acc0);   acc1 = fmaf(d2, v1.z, acc1);
      float d3 = fmaf(k2b, d2, -d1);
      accA0 = fmaf(d3, v0.w, accA0); accA1 = fmaf(d3, v1.w, accA1);
      cm2 = d2; cm1 = d3;
    }
    for (int i0 = 16; i0 < 128; i0 += 16) {
      float b0f = (float)(2 * i0 + 1);
      float ca = cy_elem(b0f, kf, sc);                   // anchor i0 (R1-exact expr)
      float cb = cy_elem(__fadd_rn(b0f, 2.0f), kf, sc);  // anchor i0+1 (R1-exact expr)
      float4 u0 = *(const float4*)&us[i0];
      float4 u1 = *(const float4*)&us[128 + i0];
      acc0 = fmaf(ca, u0.x, acc0);   acc1 = fmaf(ca, u1.x, acc1);
      accA0 = fmaf(cb, u0.y, accA0); accA1 = fmaf(cb, u1.y, accA1);
      float d2 = fmaf(k2b, cb, -ca);
      acc0 = fmaf(d2, u0.z, acc0);   acc1 = fmaf(d2, u1.z, acc1);
      float d3 = fmaf(k2b, d2, -cb);
      accA0 = fmaf(d3, u0.w, accA0); accA1 = fmaf(d3, u1.w, accA1);
      cm2 = d2; cm1 = d3;
#pragma unroll
      for (int q = 1; q < 4; ++q) {
        int i = i0 + (q << 2);
        float4 v0 = *(const float4*)&us[i];
        float4 v1 = *(const float4*)&us[128 + i];
        float d0 = fmaf(k2b, cm1, -cm2);
        acc0 = fmaf(d0, v0.x, acc0);   acc1 = fmaf(d0, v1.x, acc1);
        float d1 = fmaf(k2b, d0, -cm1);
        accA0 = fmaf(d1, v0.y, accA0); accA1 = fmaf(d1, v1.y, accA1);
        float e2 = fmaf(k2b, d1, -d0);
        acc0 = fmaf(e2, v0.z, acc0);   acc1 = fmaf(e2, v1.z, acc1);
        float e3 = fmaf(k2b, e2, -d1);
        accA0 = fmaf(e3, v0.w, accA0); accA1 = fmaf(e3, v1.w, accA1);
        cm2 = e2; cm1 = e3;
      }
    }
    acc0 += accA0;
    acc1 += accA1;
    const float w0 = PI_F / 512.0f;  // exact pow2 scale of pi_f
    float ky = __fmul_rn(kf, w0);
    float kx = __fmul_rn(jf, w0);
    float fsv = __fsqrt_rn(__fadd_rn(__fmul_rn(ky, ky), __fmul_rn(kx, kx)));
    float cs = __cosf(__fmul_rn(fsv, 32.0f));  // t-step cosine, hoisted
    kq[tid] = make_float4(fsv, __fmul_rn(a, acc0), __fmul_rn(a, acc1), cs);
  }
  __syncthreads();
  // Phase C: thread (kg, tg); t = tg + 32n (n=0..15); k in [32kg, 32kg+32)
  int kg = tid >> 5, tg = tid & 31;
  int kbeg = kg << 5;
  float tfa = (float)tg;         // anchor t
  float tfb = (float)(tg + 32);  // anchor t + 32
  float a0[16], a1[16];
#pragma unroll
  for (int n = 0; n < 16; ++n) { a0[n] = 0.0f; a1[n] = 0.0f; }
  for (int kk = 0; kk < 32; ++kk) {
    float4 q = kq[kbeg + kk];
    float F = q.x, m0 = q.y, m1 = q.z;
    float k2 = q.w + q.w;  // 2*cos(32F), exact *2
    float ca = __cosf(__fmul_rn(F, tfa));  // bit-matches ref at t = tg
    float cb = __cosf(__fmul_rn(F, tfb));  // bit-matches ref at t = tg+32
    a0[0] = fmaf(ca, m0, a0[0]); a1[0] = fmaf(ca, m1, a1[0]);
    a0[1] = fmaf(cb, m0, a0[1]); a1[1] = fmaf(cb, m1, a1[1]);
#pragma unroll
    for (int n = 2; n < 16; ++n) {
      float cn = fmaf(k2, cb, -ca);
      a0[n] = fmaf(cn, m0, a0[n]); a1[n] = fmaf(cn, m1, a1[n]);
      ca = cb; cb = cn;
    }
  }
  // reduce b0 then b1 across kg (ascending, fixed order); red[kg][t] 2-way (free)
#pragma unroll
  for (int n = 0; n < 16; ++n) red[kg][(n << 5) + tg] = a0[n];
  __syncthreads();
  float s0 = red[0][tid];
#pragma unroll
  for (int g = 1; g < 16; ++g) s0 += red[g][tid];
  __syncthreads();
#pragma unroll
  for (int n = 0; n < 16; ++n) red[kg][(n << 5) + tg] = a1[n];
  __syncthreads();
  float s1 = red[0][tid];
#pragma unroll
  for (int g = 1; g < 16; ++g) s1 += red[g][tid];
  Vt[(j << 10) + tid] = s0;
  Vt[(j << 10) + 512 + tid] = s1;
}

// stageC v5 (parity-symmetric): R21-verified byte-for-byte. block = t (grid 512, 256 thr).
__global__ __launch_bounds__(256, 4) void stageC_kernel(const float* __restrict__ Vt,
                                                        float* __restrict__ out,
                                                        float* __restrict__ partial) {
  __shared__ float vq[1024];  // [j][2] = {b0, b1} for this block's t
  int t = blockIdx.x;
  int tid = threadIdx.x;
  {
    const float* b0p = Vt + (tid << 10);
    const float* b1p = b0p + 512;
    vq[2 * tid] = b0p[t];
    vq[2 * tid + 1] = b1p[t];
    const float* b0q = Vt + ((tid + 256) << 10);
    const float* b1q = b0q + 512;
    vq[2 * tid + 512] = b0q[t];
    vq[2 * tid + 513] = b1q[t];
  }
  __syncthreads();
  int l = tid;
  float t1 = __fmul_rn(PI_F, (float)(2 * l + 1));
  float cth = __cosf(__fmul_rn(t1, 1.0f) * (1.0f / 1024.0f));
  float k2 = cth + cth;  // exact *2
  float cy0 = __fmul_rn(1.0f / __fsqrt_rn(2048.0f), 2.0f);
  float c16 = __fmul_rn(cy0, 16.0f);
  float e0, e1, o0, o1;
  float c_m1, c_m2;
  {
    float2 v0 = *(const float2*)&vq[0];
    e0 = __fmul_rn(c16, v0.x);
    e1 = __fmul_rn(c16, v0.y);
    float2 v1 = *(const float2*)&vq[2];
    o0 = __fmul_rn(cth, v1.x);
    o1 = __fmul_rn(cth, v1.y);
    float c2v = __cosf(__fmul_rn(t1, 2.0f) * (1.0f / 1024.0f));
    float2 v2 = *(const float2*)&vq[4];
    e0 = fmaf(c2v, v2.x, e0); e1 = fmaf(c2v, v2.y, e1);
    c_m2 = cth; c_m1 = c2v;
#pragma unroll
    for (int j = 3; j < 16; ++j) {
      float cn = fmaf(k2, c_m1, -c_m2);
      float2 v = *(const float2*)&vq[j << 1];
      if (j & 1) { o0 = fmaf(cn, v.x, o0); o1 = fmaf(cn, v.y, o1); }
      else       { e0 = fmaf(cn, v.x, e0); e1 = fmaf(cn, v.y, e1); }
      c_m2 = c_m1; c_m1 = cn;
    }
  }
  for (int j0 = 16; j0 < 512; j0 += 16) {
    float jb = (float)j0;
    float ca = __cosf(__fmul_rn(t1, jb) * (1.0f / 1024.0f));                      // even
    float cb = __cosf(__fmul_rn(t1, __fadd_rn(jb, 1.0f)) * (1.0f / 1024.0f));    // odd
    float2 va = *(const float2*)&vq[j0 << 1];
    e0 = fmaf(ca, va.x, e0); e1 = fmaf(ca, va.y, e1);
    float2 vb = *(const float2*)&vq[(j0 + 1) << 1];
    o0 = fmaf(cb, vb.x, o0); o1 = fmaf(cb, vb.y, o1);
    c_m2 = ca; c_m1 = cb;
#pragma unroll
    for (int n = 2; n < 16; ++n) {
      float cn = fmaf(k2, c_m1, -c_m2);
      float2 v = *(const float2*)&vq[(j0 + n) << 1];
      if (n & 1) { o0 = fmaf(cn, v.x, o0); o1 = fmaf(cn, v.y, o1); }
      else       { e0 = fmaf(cn, v.x, e0); e1 = fmaf(cn, v.y, e1); }
      c_m2 = c_m1; c_m1 = cn;
    }
  }
  float pA0 = __fmul_rn(e0 + o0, 0.0625f) / 3.0f;  // (t, l, b0)
  float pA1 = __fmul_rn(e1 + o1, 0.0625f) / 3.0f;  // (t, l, b1)
  float pB0 = __fmul_rn(e0 - o0, 0.0625f) / 3.0f;  // (t, 511-l, b0)
  float pB1 = __fmul_rn(e1 - o1, 0.0625f) / 3.0f;  // (t, 511-l, b1)
  int lr = 511 - l;
  out[(t << 9) + l] = pA0;
  out[HALF_N + (t << 9) + l] = pA1;
  out[(t << 9) + lr] = pB0;
  out[HALF_N + (t << 9) + lr] = pB1;
  float s0 = pA0 + pB0, q0 = fmaf(pA0, pA0, pB0 * pB0);
  float s1 = pA1 + pB1, q1 = fmaf(pA1, pA1, pB1 * pB1);
  for (int off = 32; off > 0; off >>= 1) {
    s0 += __shfl_down(s0, off);
    q0 += __shfl_down(q0, off);
    s1 += __shfl_down(s1, off);
    q1 += __shfl_down(q1, off);
  }
  __shared__ float red[4][4];
  int wave = tid >> 6;
  if ((tid & 63) == 0) {
    red[wave][0] = s0; red[wave][1] = q0; red[wave][2] = s1; red[wave][3] = q1;
  }
  __syncthreads();
  if (tid == 0) {
    float a0 = 0.f, a1 = 0.f, a2 = 0.f, a3 = 0.f;
    for (int wv = 0; wv < 4; ++wv) {
      a0 += red[wv][0]; a1 += red[wv][1]; a2 += red[wv][2]; a3 += red[wv][3];
    }
    partial[blockIdx.x * 4 + 0] = a0;
    partial[blockIdx.x * 4 + 1] = a1;
    partial[blockIdx.x * 4 + 2] = a2;
    partial[blockIdx.x * 4 + 3] = a3;
  }
}

// Fused stats + noise: redundant partial reduce (512 quads) -> (std0,std1), then threefry noise.
// element i -> threefry2x32(key=(0,42), ctr=(0,i)), bits = o0^o1
__global__ __launch_bounds__(256) void noise_kernel(float* __restrict__ out,
                                                    const float* __restrict__ partial) {
  int tid = threadIdx.x;
  const float4* pq = (const float4*)partial;  // 512 quads {s0,q0,s1,q1}
  float4 pa = pq[tid];
  float4 pb = pq[tid + 256];
  float s0 = pa.x + pb.x, q0 = pa.y + pb.y, s1 = pa.z + pb.z, q1 = pa.w + pb.w;
  for (int off = 32; off > 0; off >>= 1) {
    s0 += __shfl_down(s0, off);
    q0 += __shfl_down(q0, off);
    s1 += __shfl_down(s1, off);
    q1 += __shfl_down(q1, off);
  }
  __shared__ float red[4][4];
  int wave = tid >> 6;
  if ((tid & 63) == 0) {
    red[wave][0] = s0; red[wave][1] = q0; red[wave][2] = s1; red[wave][3] = q1;
  }
  __syncthreads();
  float S = red[0][0] + red[1][0] + red[2][0] + red[3][0];
  float Q = red[0][1] + red[1][1] + red[2][1] + red[3][1];
  float S2 = red[0][2] + red[1][2] + red[2][2] + red[3][2];
  float Q2 = red[0][3] + red[1][3] + red[2][3] + red[3][3];
  const float invN = 1.0f / 262144.0f;
  float m0 = S * invN, m1 = S2 * invN;
  float std0 = __fsqrt_rn(fmaxf(Q * invN - m0 * m0, 0.0f));
  float std1 = __fsqrt_rn(fmaxf(Q2 * invN - m1 * m1, 0.0f));

  int i = blockIdx.x * 256 + tid;  // < 524288
  uint32_t x0 = 0u;
  uint32_t x1 = (uint32_t)i;
  const uint32_t k0 = 0u, k1 = 42u;
  const uint32_t k2 = k0 ^ k1 ^ 0x1BD11BDAu;
  x0 += k0; x1 += k1;
#define QR(r) x0 += x1; x1 = rotl32(x1, r); x1 ^= x0;
  QR(13) QR(15) QR(26) QR(6)
  x0 += k1; x1 += k2 + 1u;
  QR(17) QR(29) QR(16) QR(24)
  x0 += k2; x1 += k0 + 2u;
  QR(13) QR(15) QR(26) QR(6)
  x0 += k0; x1 += k1 + 3u;
  QR(17) QR(29) QR(16) QR(24)
  x0 += k1; x1 += k2 + 4u;
  QR(13) QR(15) QR(26) QR(6)
  x0 += k2; x1 += k0 + 5u;
#undef QR
  uint32_t bits = x0 ^ x1;
  const float lo = __uint_as_float(0xBF7FFFFFu);  // nextafter(-1,0)
  float f = __uint_as_float((bits >> 9) | 0x3F800000u) - 1.0f;
  float u = fmaxf(lo, __fadd_rn(__fmul_rn(f, 2.0f), lo));
  const float sqrt2 = 1.41421356237309515f;
  out[i] += (i < HALF_N ? std0 : std1) * (sqrt2 * erfinv_xla(u));
}

extern "C" void kernel_launch(void* const* d_in, const int* in_sizes, int n_in,
                              void* d_out, int out_size, void* d_ws, size_t ws_size,
                              hipStream_t stream) {
  const float* x = (const float*)d_in[0];
  float* ws = (float*)d_ws;
  float* Vt      = ws;
  float* partial = ws + 524288;
  float* out = (float*)d_out;

  stageB_kernel<<<512, 512, 0, stream>>>(x, Vt);
  stageC_kernel<<<512, 256, 0, stream>>>(Vt, out, partial);
  noise_kernel<<<2048, 256, 0, stream>>>(out, partial);
}

// Round 14
// 97.156 us; speedup vs baseline: 1.2352x; 1.0014x over previous
//
#include <hip/hip_runtime.h>
#include <stdint.h>
#include <math.h>

// PhysicsForwardModel: B=2, Nz=Nx=128, Ly=Lx=512.
// out[b,t,l] = (1/3) * sum_j Cy[j,l] * sum_k cos(F[k,j]*t) * a[k] * (Cy[:,:128] x[b] Cy[:,128:256]^T)[k,j]
//              + std_b * N(0,1)  (JAX threefry key=42, partitionable counters, XLA erfinv)
// R23: stageB/noise = R22 byte-for-byte. ONE change: stageC consumes vq via ds_read_b128
//      pairs (even j 16B-aligned in the [j][2] layout; one b128 = {j,j+1}x{b0,b1}).
//      LDS broadcast count halves 512 -> 256/thread (stageC's ~14us LDS-pipe term).
//      Coefficient values and fma order identical to R22 -> bit-identical out.

#define HALF_N 262144  // 512*512 per-batch elements
#define PI_F 3.14159274101257324f

// ws layout (floats): Vt [0..524288) [j][b][t]; partial [524288..526336) 512 x {s0,q0,s1,q1}

__device__ __forceinline__ uint32_t rotl32(uint32_t v, int r) {
  return (v << r) | (v >> (32 - r));
}

// XLA ErfInv32 (Giles) -- matches reference's lax.erf_inv
__device__ __forceinline__ float erfinv_xla(float x) {
  float w = -log1pf(__fmul_rn(-x, x));
  float p;
  if (w < 5.0f) {
    w = w - 2.5f;
    p = 2.81022636e-08f;
    p = fmaf(p, w, 3.43273939e-07f);
    p = fmaf(p, w, -3.5233877e-06f);
    p = fmaf(p, w, -4.39150654e-06f);
    p = fmaf(p, w, 0.00021858087f);
    p = fmaf(p, w, -0.00125372503f);
    p = fmaf(p, w, -0.00417768164f);
    p = fmaf(p, w, 0.246640727f);
    p = fmaf(p, w, 1.50140941f);
  } else {
    w = __fsqrt_rn(w) - 3.0f;
    p = -0.000200214257f;
    p = fmaf(p, w, 0.000100950558f);
    p = fmaf(p, w, 0.00134934322f);
    p = fmaf(p, w, -0.00367342844f);
    p = fmaf(p, w, 0.00573950773f);
    p = fmaf(p, w, -0.0076224613f);
    p = fmaf(p, w, 0.00943887047f);
    p = fmaf(p, w, 1.00167406f);
    p = fmaf(p, w, 2.83297682f);
  }
  return p * x;
}

// Cy[k,n] = sc(k) * 2 * cos(pi*(2n+1)*k/1024), with n2p1 = (float)(2n+1) exact
__device__ __forceinline__ float cy_elem(float n2p1, float kf, float sc) {
  float t1 = __fmul_rn(PI_F, n2p1);
  float arg = __fmul_rn(t1, kf) * (1.0f / 1024.0f);
  return __fmul_rn(sc, __fmul_rn(2.0f, __cosf(arg)));
}

// fusedB, block = j (grid 512, 512 threads):  [R22-verified, byte-identical]
__global__ __launch_bounds__(512, 4) void stageB_kernel(const float* __restrict__ x,
                                                        float* __restrict__ Vt) {
  __shared__ float cyl[128];
  __shared__ float us[256];
  __shared__ float4 kq[512];
  __shared__ float red[16][512];
  int j = blockIdx.x;
  int tid = threadIdx.x;
  float jf = (float)j;
  if (tid < 128) {
    float scj = (j == 0) ? (1.0f / __fsqrt_rn(2048.0f)) : 0.03125f;
    cyl[tid] = cy_elem((float)(2 * (128 + tid) + 1), jf, scj);
  }
  __syncthreads();
  if (tid < 256) {
    int b = tid >> 7, i = tid & 127;
    const float* xr = x + (b * 128 + i) * 128;
    float accA = 0.0f, accB = 0.0f;
    for (int jj = 0; jj < 128; jj += 8) {
      float4 xa = *(const float4*)&xr[jj];
      float4 xb = *(const float4*)&xr[jj + 4];
      float4 ca = *(const float4*)&cyl[jj];
      float4 cb = *(const float4*)&cyl[jj + 4];
      accA = fmaf(xa.x, ca.x, accA); accB = fmaf(xa.y, ca.y, accB);
      accA = fmaf(xa.z, ca.z, accA); accB = fmaf(xa.w, ca.w, accB);
      accA = fmaf(xb.x, cb.x, accA); accB = fmaf(xb.y, cb.y, accB);
      accA = fmaf(xb.z, cb.z, accA); accB = fmaf(xb.w, cb.w, accB);
    }
    us[tid] = accA + accB;
  }
  __syncthreads();
  {
    float kf = (float)tid;
    float sc = (tid == 0) ? (1.0f / __fsqrt_rn(2048.0f)) : 0.03125f;
    // coefficient recurrence step: 2*cos(pi*k/512)  (PI_F/512 exact pow2 scale)
    float thc = __cosf(__fmul_rn(kf, PI_F / 512.0f));
    float k2b = thc + thc;  // exact *2
    float a = cy_elem(1.0f, kf, sc);   // i=0 anchor (bit-identical)
    float c1 = cy_elem(3.0f, kf, sc);  // i=1 anchor (bit-identical)
    float acc0 = __fmul_rn(a, us[0]);
    float acc1 = __fmul_rn(a, us[128]);
    float accA0 = 0.f, accA1 = 0.f;
    acc0 = fmaf(c1, us[1], acc0);   acc1 = fmaf(c1, us[129], acc1);
    float cc2 = fmaf(k2b, c1, -a);      // i=2 (recurred)
    accA0 = fmaf(cc2, us[2], accA0); accA1 = fmaf(cc2, us[130], accA1);
    float cc3 = fmaf(k2b, cc2, -c1);    // i=3
    acc0 = fmaf(cc3, us[3], acc0);   acc1 = fmaf(cc3, us[131], acc1);
    float cm2 = cc2, cm1 = cc3;
#pragma unroll
    for (int q = 1; q < 4; ++q) {  // i = 4..15
      int i = q << 2;
      float4 v0 = *(const float4*)&us[i];
      float4 v1 = *(const float4*)&us[128 + i];
      float d0 = fmaf(k2b, cm1, -cm2);
      acc0 = fmaf(d0, v0.x, acc0);   acc1 = fmaf(d0, v1.x, acc1);
      float d1 = fmaf(k2b, d0, -cm1);
      accA0 = fmaf(d1, v0.y, accA0); accA1 = fmaf(d1, v1.y, accA1);
      float d2 = fmaf(k2b, d1, -d0);
      acc0 = fmaf(d2, v0.z, acc0);   acc1 = fmaf(d2, v1.z, acc1);
      float d3 = fmaf(k2b, d2, -d1);
      accA0 = fmaf(d3, v0.w, accA0); accA1 = fmaf(d3, v1.w, accA1);
      cm2 = d2; cm1 = d3;
    }
    for (int i0 = 16; i0 < 128; i0 += 16) {
      float b0f = (float)(2 * i0 + 1);
      float ca = cy_elem(b0f, kf, sc);                   // anchor i0 (R1-exact expr)
      float cb = cy_elem(__fadd_rn(b0f, 2.0f), kf, sc);  // anchor i0+1 (R1-exact expr)
      float4 u0 = *(const float4*)&us[i0];
      float4 u1 = *(const float4*)&us[128 + i0];
      acc0 = fmaf(ca, u0.x, acc0);   acc1 = fmaf(ca, u1.x, acc1);
      accA0 = fmaf(cb, u0.y, accA0); accA1 = fmaf(cb, u1.y, accA1);
      float d2 = fmaf(k2b, cb, -ca);
      acc0 = fmaf(d2, u0.z, acc0);   acc1 = fmaf(d2, u1.z, acc1);
      float d3 = fmaf(k2b, d2, -cb);
      accA0 = fmaf(d3, u0.w, accA0); accA1 = fmaf(d3, u1.w, accA1);
      cm2 = d2; cm1 = d3;
#pragma unroll
      for (int q = 1; q < 4; ++q) {
        int i = i0 + (q << 2);
        float4 v0 = *(const float4*)&us[i];
        float4 v1 = *(const float4*)&us[128 + i];
        float d0 = fmaf(k2b, cm1, -cm2);
        acc0 = fmaf(d0, v0.x, acc0);   acc1 = fmaf(d0, v1.x, acc1);
        float d1 = fmaf(k2b, d0, -cm1);
        accA0 = fmaf(d1, v0.y, accA0); accA1 = fmaf(d1, v1.y, accA1);
        float e2 = fmaf(k2b, d1, -d0);
        acc0 = fmaf(e2, v0.z, acc0);   acc1 = fmaf(e2, v1.z, acc1);
        float e3 = fmaf(k2b, e2, -d1);
        accA0 = fmaf(e3, v0.w, accA0); accA1 = fmaf(e3, v1.w, accA1);
        cm2 = e2; cm1 = e3;
      }
    }
    acc0 += accA0;
    acc1 += accA1;
    const float w0 = PI_F / 512.0f;  // exact pow2 scale of pi_f
    float ky = __fmul_rn(kf, w0);
    float kx = __fmul_rn(jf, w0);
    float fsv = __fsqrt_rn(__fadd_rn(__fmul_rn(ky, ky), __fmul_rn(kx, kx)));
    float cs = __cosf(__fmul_rn(fsv, 32.0f));  // t-step cosine, hoisted
    kq[tid] = make_float4(fsv, __fmul_rn(a, acc0), __fmul_rn(a, acc1), cs);
  }
  __syncthreads();
  // Phase C: thread (kg, tg); t = tg + 32n (n=0..15); k in [32kg, 32kg+32)
  int kg = tid >> 5, tg = tid & 31;
  int kbeg = kg << 5;
  float tfa = (float)tg;         // anchor t
  float tfb = (float)(tg + 32);  // anchor t + 32
  float a0[16], a1[16];
#pragma unroll
  for (int n = 0; n < 16; ++n) { a0[n] = 0.0f; a1[n] = 0.0f; }
  for (int kk = 0; kk < 32; ++kk) {
    float4 q = kq[kbeg + kk];
    float F = q.x, m0 = q.y, m1 = q.z;
    float k2 = q.w + q.w;  // 2*cos(32F), exact *2
    float ca = __cosf(__fmul_rn(F, tfa));  // bit-matches ref at t = tg
    float cb = __cosf(__fmul_rn(F, tfb));  // bit-matches ref at t = tg+32
    a0[0] = fmaf(ca, m0, a0[0]); a1[0] = fmaf(ca, m1, a1[0]);
    a0[1] = fmaf(cb, m0, a0[1]); a1[1] = fmaf(cb, m1, a1[1]);
#pragma unroll
    for (int n = 2; n < 16; ++n) {
      float cn = fmaf(k2, cb, -ca);
      a0[n] = fmaf(cn, m0, a0[n]); a1[n] = fmaf(cn, m1, a1[n]);
      ca = cb; cb = cn;
    }
  }
  // reduce b0 then b1 across kg (ascending, fixed order); red[kg][t] 2-way (free)
#pragma unroll
  for (int n = 0; n < 16; ++n) red[kg][(n << 5) + tg] = a0[n];
  __syncthreads();
  float s0 = red[0][tid];
#pragma unroll
  for (int g = 1; g < 16; ++g) s0 += red[g][tid];
  __syncthreads();
#pragma unroll
  for (int n = 0; n < 16; ++n) red[kg][(n << 5) + tg] = a1[n];
  __syncthreads();
  float s1 = red[0][tid];
#pragma unroll
  for (int g = 1; g < 16; ++g) s1 += red[g][tid];
  Vt[(j << 10) + tid] = s0;
  Vt[(j << 10) + 512 + tid] = s1;
}

// stageC v6: parity-symmetric (R21) + b128 j-pairs. block = t (grid 512, 256 threads).
// Same coefficient values and fma order as R22 -> bit-identical out.
__global__ __launch_bounds__(256, 4) void stageC_kernel(const float* __restrict__ Vt,
                                                        float* __restrict__ out,
                                                        float* __restrict__ partial) {
  __shared__ float vq[1024];  // [j][2] = {b0, b1} for this block's t
  int t = blockIdx.x;
  int tid = threadIdx.x;
  {
    const float* b0p = Vt + (tid << 10);
    const float* b1p = b0p + 512;
    vq[2 * tid] = b0p[t];
    vq[2 * tid + 1] = b1p[t];
    const float* b0q = Vt + ((tid + 256) << 10);
    const float* b1q = b0q + 512;
    vq[2 * tid + 512] = b0q[t];
    vq[2 * tid + 513] = b1q[t];
  }
  __syncthreads();
  int l = tid;
  float t1 = __fmul_rn(PI_F, (float)(2 * l + 1));
  float cth = __cosf(__fmul_rn(t1, 1.0f) * (1.0f / 1024.0f));
  float k2 = cth + cth;  // exact *2
  float cy0 = __fmul_rn(1.0f / __fsqrt_rn(2048.0f), 2.0f);
  float c16 = __fmul_rn(cy0, 16.0f);
  float e0, e1, o0, o1;
  float c_m1, c_m2;
  {
    // pair (0,1): b128 = {j0.b0, j0.b1, j1.b0, j1.b1}
    float4 v01 = *(const float4*)&vq[0];
    e0 = __fmul_rn(c16, v01.x);
    e1 = __fmul_rn(c16, v01.y);
    o0 = __fmul_rn(cth, v01.z);
    o1 = __fmul_rn(cth, v01.w);
    float c2v = __cosf(__fmul_rn(t1, 2.0f) * (1.0f / 1024.0f));
    // pair (2,3): c2 anchor, c3 recurred
    float4 v23 = *(const float4*)&vq[4];
    e0 = fmaf(c2v, v23.x, e0); e1 = fmaf(c2v, v23.y, e1);
    float c3 = fmaf(k2, c2v, -cth);
    o0 = fmaf(c3, v23.z, o0); o1 = fmaf(c3, v23.w, o1);
    c_m2 = c2v; c_m1 = c3;
#pragma unroll
    for (int j = 4; j < 16; j += 2) {
      float4 v = *(const float4*)&vq[j << 1];
      float cj = fmaf(k2, c_m1, -c_m2);
      e0 = fmaf(cj, v.x, e0); e1 = fmaf(cj, v.y, e1);
      float cj1 = fmaf(k2, cj, -c_m1);
      o0 = fmaf(cj1, v.z, o0); o1 = fmaf(cj1, v.w, o1);
      c_m2 = cj; c_m1 = cj1;
    }
  }
  for (int j0 = 16; j0 < 512; j0 += 16) {
    float jb = (float)j0;
    float ca = __cosf(__fmul_rn(t1, jb) * (1.0f / 1024.0f));                      // even
    float cb = __cosf(__fmul_rn(t1, __fadd_rn(jb, 1.0f)) * (1.0f / 1024.0f));    // odd
    float4 vab = *(const float4*)&vq[j0 << 1];
    e0 = fmaf(ca, vab.x, e0); e1 = fmaf(ca, vab.y, e1);
    o0 = fmaf(cb, vab.z, o0); o1 = fmaf(cb, vab.w, o1);
    c_m2 = ca; c_m1 = cb;
#pragma unroll
    for (int n = 2; n < 16; n += 2) {
      float4 v = *(const float4*)&vq[(j0 + n) << 1];
      float cj = fmaf(k2, c_m1, -c_m2);
      e0 = fmaf(cj, v.x, e0); e1 = fmaf(cj, v.y, e1);
      float cj1 = fmaf(k2, cj, -c_m1);
      o0 = fmaf(cj1, v.z, o0); o1 = fmaf(cj1, v.w, o1);
      c_m2 = cj; c_m1 = cj1;
    }
  }
  float pA0 = __fmul_rn(e0 + o0, 0.0625f) / 3.0f;  // (t, l, b0)
  float pA1 = __fmul_rn(e1 + o1, 0.0625f) / 3.0f;  // (t, l, b1)
  float pB0 = __fmul_rn(e0 - o0, 0.0625f) / 3.0f;  // (t, 511-l, b0)
  float pB1 = __fmul_rn(e1 - o1, 0.0625f) / 3.0f;  // (t, 511-l, b1)
  int lr = 511 - l;
  out[(t << 9) + l] = pA0;
  out[HALF_N + (t << 9) + l] = pA1;
  out[(t << 9) + lr] = pB0;
  out[HALF_N + (t << 9) + lr] = pB1;
  float s0 = pA0 + pB0, q0 = fmaf(pA0, pA0, pB0 * pB0);
  float s1 = pA1 + pB1, q1 = fmaf(pA1, pA1, pB1 * pB1);
  for (int off = 32; off > 0; off >>= 1) {
    s0 += __shfl_down(s0, off);
    q0 += __shfl_down(q0, off);
    s1 += __shfl_down(s1, off);
    q1 += __shfl_down(q1, off);
  }
  __shared__ float red[4][4];
  int wave = tid >> 6;
  if ((tid & 63) == 0) {
    red[wave][0] = s0; red[wave][1] = q0; red[wave][2] = s1; red[wave][3] = q1;
  }
  __syncthreads();
  if (tid == 0) {
    float a0 = 0.f, a1 = 0.f, a2 = 0.f, a3 = 0.f;
    for (int wv = 0; wv < 4; ++wv) {
      a0 += red[wv][0]; a1 += red[wv][1]; a2 += red[wv][2]; a3 += red[wv][3];
    }
    partial[blockIdx.x * 4 + 0] = a0;
    partial[blockIdx.x * 4 + 1] = a1;
    partial[blockIdx.x * 4 + 2] = a2;
    partial[blockIdx.x * 4 + 3] = a3;
  }
}

// Fused stats + noise: redundant partial reduce (512 quads) -> (std0,std1), then threefry noise.
// element i -> threefry2x32(key=(0,42), ctr=(0,i)), bits = o0^o1
__global__ __launch_bounds__(256) void noise_kernel(float* __restrict__ out,
                                                    const float* __restrict__ partial) {
  int tid = threadIdx.x;
  const float4* pq = (const float4*)partial;  // 512 quads {s0,q0,s1,q1}
  float4 pa = pq[tid];
  float4 pb = pq[tid + 256];
  float s0 = pa.x + pb.x, q0 = pa.y + pb.y, s1 = pa.z + pb.z, q1 = pa.w + pb.w;
  for (int off = 32; off > 0; off >>= 1) {
    s0 += __shfl_down(s0, off);
    q0 += __shfl_down(q0, off);
    s1 += __shfl_down(s1, off);
    q1 += __shfl_down(q1, off);
  }
  __shared__ float red[4][4];
  int wave = tid >> 6;
  if ((tid & 63) == 0) {
    red[wave][0] = s0; red[wave][1] = q0; red[wave][2] = s1; red[wave][3] = q1;
  }
  __syncthreads();
  float S = red[0][0] + red[1][0] + red[2][0] + red[3][0];
  float Q = red[0][1] + red[1][1] + red[2][1] + red[3][1];
  float S2 = red[0][2] + red[1][2] + red[2][2] + red[3][2];
  float Q2 = red[0][3] + red[1][3] + red[2][3] + red[3][3];
  const float invN = 1.0f / 262144.0f;
  float m0 = S * invN, m1 = S2 * invN;
  float std0 = __fsqrt_rn(fmaxf(Q * invN - m0 * m0, 0.0f));
  float std1 = __fsqrt_rn(fmaxf(Q2 * invN - m1 * m1, 0.0f));

  int i = blockIdx.x * 256 + tid;  // < 524288
  uint32_t x0 = 0u;
  uint32_t x1 = (uint32_t)i;
  const uint32_t k0 = 0u, k1 = 42u;
  const uint32_t k2 = k0 ^ k1 ^ 0x1BD11BDAu;
  x0 += k0; x1 += k1;
#define QR(r) x0 += x1; x1 = rotl32(x1, r); x1 ^= x0;
  QR(13) QR(15) QR(26) QR(6)
  x0 += k1; x1 += k2 + 1u;
  QR(17) QR(29) QR(16) QR(24)
  x0 += k2; x1 += k0 + 2u;
  QR(13) QR(15) QR(26) QR(6)
  x0 += k0; x1 += k1 + 3u;
  QR(17) QR(29) QR(16) QR(24)
  x0 += k1; x1 += k2 + 4u;
  QR(13) QR(15) QR(26) QR(6)
  x0 += k2; x1 += k0 + 5u;
#undef QR
  uint32_t bits = x0 ^ x1;
  const float lo = __uint_as_float(0xBF7FFFFFu);  // nextafter(-1,0)
  float f = __uint_as_float((bits >> 9) | 0x3F800000u) - 1.0f;
  float u = fmaxf(lo, __fadd_rn(__fmul_rn(f, 2.0f), lo));
  const float sqrt2 = 1.41421356237309515f;
  out[i] += (i < HALF_N ? std0 : std1) * (sqrt2 * erfinv_xla(u));
}

extern "C" void kernel_launch(void* const* d_in, const int* in_sizes, int n_in,
                              void* d_out, int out_size, void* d_ws, size_t ws_size,
                              hipStream_t stream) {
  const float* x = (const float*)d_in[0];
  float* ws = (float*)d_ws;
  float* Vt      = ws;
  float* partial = ws + 524288;
  float* out = (float*)d_out;

  stageB_kernel<<<512, 512, 0, stream>>>(x, Vt);
  stageC_kernel<<<512, 256, 0, stream>>>(Vt, out, partial);
  noise_kernel<<<2048, 256, 0, stream>>>(out, partial);
}